// Round 8
// baseline (938.038 us; speedup 1.0000x reference)
//
#include <hip/hip_runtime.h>
#include <cstdint>

#define N_NODES 20000
#define N_EDGES 320000
#define ALPHA 0.2f
#define GAT_EPS 1e-16f
#define MPAD 20096           // 157 * 128
#define SCAN_BLKS 80
#define BT_ROWS 1152         // 9 col-blocks * 128

typedef __attribute__((ext_vector_type(8))) _Float16 half8;
typedef __attribute__((ext_vector_type(4))) float f32x4;

__device__ __forceinline__ float elu1(float x) { return x > 0.f ? x : __expf(x) - 1.f; }

__device__ __forceinline__ void async16(const void* g, void* l) {
    __builtin_amdgcn_global_load_lds(
        (const __attribute__((address_space(1))) unsigned int*)g,
        (__attribute__((address_space(3))) unsigned int*)l, 16, 0, 0);
}

// ---------------- CSR build ----------------
__global__ void hist_kernel(const int* __restrict__ dst, int* __restrict__ counts, int E) {
    int e = blockIdx.x * blockDim.x + threadIdx.x;
    if (e < E) atomicAdd(&counts[dst[e]], 1);
}

__global__ void scan1_kernel(const int* __restrict__ counts, int* __restrict__ excl,
                             int* __restrict__ partial, int N) {
    __shared__ int sh[256];
    int t = threadIdx.x, b = blockIdx.x;
    int i = b * 256 + t;
    int v = (i < N) ? counts[i] : 0;
    sh[t] = v;
    __syncthreads();
    for (int d = 1; d < 256; d <<= 1) {
        int x = (t >= d) ? sh[t - d] : 0;
        __syncthreads();
        sh[t] += x;
        __syncthreads();
    }
    if (i < N) excl[i] = sh[t] - v;
    if (t == 255) partial[b] = sh[255];
}

__global__ void scan2_kernel(int* __restrict__ partial) {
    __shared__ int sh[128];
    int t = threadIdx.x;
    int v = (t < SCAN_BLKS) ? partial[t] : 0;
    sh[t] = v;
    __syncthreads();
    for (int d = 1; d < 128; d <<= 1) {
        int x = (t >= d) ? sh[t - d] : 0;
        __syncthreads();
        sh[t] += x;
        __syncthreads();
    }
    if (t < SCAN_BLKS) partial[t] = sh[t] - v;
}

__global__ void scan3_kernel(const int* __restrict__ excl, const int* __restrict__ partial,
                             int* __restrict__ rowptr, int* __restrict__ cursor, int N, int E) {
    int t = threadIdx.x, b = blockIdx.x;
    int i = b * 256 + t;
    if (i < N) {
        int v = excl[i] + partial[b];
        rowptr[i] = v;
        cursor[i] = v;
    }
    if (i == 0) rowptr[N] = E;
}

__global__ void scatter_kernel(const int* __restrict__ src, const int* __restrict__ dst,
                               int* __restrict__ cursor, int* __restrict__ esrc, int E) {
    int e = blockIdx.x * blockDim.x + threadIdx.x;
    if (e < E) {
        int p = atomicAdd(&cursor[dst[e]], 1);
        esrc[p] = src[e];
    }
}

// ---------------- packs ----------------
__global__ void pack_x16(const float* __restrict__ x, _Float16* __restrict__ A) {
    int idx = blockIdx.x * 256 + threadIdx.x;   // MPAD*64
    int r = idx >> 6, c = idx & 63;
    float v = (r < N_NODES && c < 50) ? x[r * 50 + c] : 0.f;
    A[idx] = (_Float16)v;
}

__global__ void pack_bt1(const float* __restrict__ W, _Float16* __restrict__ Bt) {
    int idx = blockIdx.x * 256 + threadIdx.x;   // 1024*64
    int c = idx >> 6, k = idx & 63;
    int h = c >> 8, f = c & 255;
    float v = (k < 50) ? W[((size_t)h * 50 + k) * 256 + f] : 0.f;
    Bt[idx] = (_Float16)v;
}

__global__ void pack_bt16(const float* __restrict__ W, _Float16* __restrict__ Bt,
                          int F, int Ctot) {
    int c = blockIdx.y;
    int k = blockIdx.x * blockDim.x + threadIdx.x;
    float v = 0.f;
    if (c < Ctot) {
        int h = c / F, f = c - h * F;
        v = W[(size_t)h * 1024 * F + (size_t)k * F + f];
    }
    Bt[(size_t)c * 1024 + k] = (_Float16)v;
}

// W~ columns appended at BT rows [Nfeat, Nfeat+2H): BT[Nfeat+j][k] = sum_f W[h,k,f]*a[h,(j>=H?F:0)+f]
// one wave per (k, j), lanes reduce over f (coalesced). gridDim.y MUST be 2*H.
__global__ __launch_bounds__(64) void wtilde_kernel(const float* __restrict__ W,
                                                    const float* __restrict__ a,
                                                    _Float16* __restrict__ BT, int Kreal,
                                                    int Kdim, int F, int H, int Nfeat) {
    int k = blockIdx.x, j = blockIdx.y;
    if (j >= 2 * H) return;                     // guard (R7 crash: OOB W reads without it)
    int lane = threadIdx.x;
    int h = j < H ? j : j - H;
    int ao = j < H ? 0 : F;
    float s = 0.f;
    if (k < Kreal) {
        const float* wp = W + ((size_t)h * Kreal + k) * F;
        const float* ap = a + (size_t)h * 2 * F + ao;
        for (int f = lane; f < F; f += 64) s += wp[f] * ap[f];
    }
#pragma unroll
    for (int off = 32; off; off >>= 1) s += __shfl_down(s, off);
    if (lane == 0) BT[(size_t)(Nfeat + j) * Kdim + k] = (_Float16)s;
}

// ---------------- fp16 MFMA GEMM, BK=64, XOR-swizzled LDS, fused score cols ----------------
__global__ __launch_bounds__(256) void gemm_f16(const _Float16* __restrict__ A,
                                                const _Float16* __restrict__ BT,
                                                _Float16* __restrict__ C,
                                                float* __restrict__ SPRE,
                                                int M, int Nfeat, int ld, int Kdim) {
    __shared__ __align__(16) _Float16 sA[128 * 64];
    __shared__ __align__(16) _Float16 sB[128 * 64];
    int t = threadIdx.x;
    int row0 = blockIdx.y * 128, col0 = blockIdx.x * 128;
    int lane = t & 63, wave = t >> 6;
    int wm = wave >> 1, wn = wave & 1;
    int fr = lane & 15;
    int fq = lane >> 4;

    const _Float16* gA = A + (size_t)row0 * Kdim;
    const _Float16* gB = BT + (size_t)col0 * Kdim;

    int sR[4], sgl[4];
#pragma unroll
    for (int i = 0; i < 4; i++) {
        int m = i * 256 + t;
        sR[i] = m >> 3;
        sgl[i] = (m & 7) ^ (sR[i] & 7);
    }

    f32x4 acc[4][4] = {};

    for (int k0 = 0; k0 < Kdim; k0 += 64) {
        __syncthreads();
#pragma unroll
        for (int i = 0; i < 4; i++) {
            const _Float16* pa = gA + (size_t)sR[i] * Kdim + k0 + sgl[i] * 8;
            const _Float16* pb = gB + (size_t)sR[i] * Kdim + k0 + sgl[i] * 8;
            async16(pa, sA + (i * 256 + t) * 8);
            async16(pb, sB + (i * 256 + t) * 8);
        }
        __syncthreads();
#pragma unroll
        for (int ks = 0; ks < 2; ks++) {
            half8 af[4], bf[4];
#pragma unroll
            for (int mt = 0; mt < 4; mt++) {
                int R = wm * 64 + mt * 16 + fr;
                int gp = (ks * 4 + fq) ^ (R & 7);
                af[mt] = *(const half8*)(sA + R * 64 + gp * 8);
            }
#pragma unroll
            for (int nt = 0; nt < 4; nt++) {
                int R = wn * 64 + nt * 16 + fr;
                int gp = (ks * 4 + fq) ^ (R & 7);
                bf[nt] = *(const half8*)(sB + R * 64 + gp * 8);
            }
#pragma unroll
            for (int mt = 0; mt < 4; mt++)
#pragma unroll
                for (int nt = 0; nt < 4; nt++)
                    acc[mt][nt] = __builtin_amdgcn_mfma_f32_16x16x32_f16(af[mt], bf[nt], acc[mt][nt], 0, 0, 0);
        }
    }

    int rbase = row0 + wm * 64 + ((lane >> 4) << 2);
    int cbase = col0 + wn * 64 + (lane & 15);
#pragma unroll
    for (int mt = 0; mt < 4; mt++)
#pragma unroll
        for (int nt = 0; nt < 4; nt++) {
            int gc = cbase + nt * 16;
            if (gc < Nfeat) {
#pragma unroll
                for (int r = 0; r < 4; r++) {
                    int gr = rbase + mt * 16 + r;
                    if (gr < M) C[(size_t)gr * ld + gc] = (_Float16)acc[mt][nt][r];
                }
            } else if (gc < Nfeat + 12) {
                int j = gc - Nfeat;
#pragma unroll
                for (int r = 0; r < 4; r++) {
                    int gr = rbase + mt * 16 + r;
                    if (gr < M) SPRE[(size_t)j * N_NODES + gr] = acc[mt][nt][r];
                }
            }
        }
}

// ---------------- per-edge attention weights; 4 nodes per block ----------------
__global__ __launch_bounds__(256) void att_kernel(const int* __restrict__ rowptr,
                                                  const int* __restrict__ esrc,
                                                  const float* __restrict__ SS,
                                                  const float* __restrict__ SD,
                                                  float* __restrict__ ATT, int N, int H) {
    int n = blockIdx.x * 4 + (threadIdx.x >> 6);
    int lane = threadIdx.x & 63;
    int start = rowptr[n], end = rowptr[n + 1];
    for (int h = 0; h < H; h++) {
        const float* ss = SS + (size_t)h * N;
        float sd = SD[(size_t)h * N + n];
        float* att = ATT + (size_t)h * N_EDGES;
        float m = -INFINITY;
        for (int e = start + lane; e < end; e += 64) {
            float sc = ss[esrc[e]] + sd;
            sc = sc > 0.f ? sc : ALPHA * sc;
            m = fmaxf(m, sc);
        }
#pragma unroll
        for (int off = 32; off; off >>= 1) m = fmaxf(m, __shfl_down(m, off));
        m = __shfl(m, 0);
        float psum = 0.f;
        for (int e = start + lane; e < end; e += 64) {
            float sc = ss[esrc[e]] + sd;
            sc = sc > 0.f ? sc : ALPHA * sc;
            float p = __expf(sc - m);
            psum += p;
            att[e] = p;
        }
#pragma unroll
        for (int off = 32; off; off >>= 1) psum += __shfl_down(psum, off);
        psum = __shfl(psum, 0);
        float inv = 1.f / (psum + GAT_EPS);
        for (int e = start + lane; e < end; e += 64) att[e] *= inv;
    }
}

// ---------------- aggregate Fout=256 layers: 64-feature XCD tiles, q-split, 4 nodes/block ----
// block id = nq*8 + tile; tile -> head tile>>1, 64-col chunk tile&1; launch q picks 128-half.
// tile t pins to XCD t (id%8 stable); per-XCD hot slice = 20000 x 64 x 2B = 2.5 MB.
__global__ __launch_bounds__(256) void agg256_kernel(const _Float16* __restrict__ WH16,
                                                     const int* __restrict__ rowptr,
                                                     const int* __restrict__ esrc,
                                                     const float* __restrict__ ATT,
                                                     _Float16* __restrict__ X16,
                                                     int use_skip, int q) {
    int id = blockIdx.x;
    int tile = id & 7, nq = id >> 3;
    int n = nq * 4 + (threadIdx.x >> 6);
    int lane = threadIdx.x & 63;
    int h = tile >> 1, sub = tile & 1;
    int base = h * 256 + q * 128 + sub * 64 + lane;
    int start = rowptr[n], end = rowptr[n + 1];
    const float* ap = ATT + (size_t)h * N_EDGES;
    const _Float16* W = WH16 + base;
    float acc = 0.f;
    int e = start;
    for (; e + 8 <= end; e += 8) {
        int i0 = esrc[e],     i1 = esrc[e + 1], i2 = esrc[e + 2], i3 = esrc[e + 3];
        int i4 = esrc[e + 4], i5 = esrc[e + 5], i6 = esrc[e + 6], i7 = esrc[e + 7];
        float w0 = (float)W[(size_t)i0 * 1024], w1 = (float)W[(size_t)i1 * 1024];
        float w2 = (float)W[(size_t)i2 * 1024], w3 = (float)W[(size_t)i3 * 1024];
        float w4 = (float)W[(size_t)i4 * 1024], w5 = (float)W[(size_t)i5 * 1024];
        float w6 = (float)W[(size_t)i6 * 1024], w7 = (float)W[(size_t)i7 * 1024];
        acc += ap[e] * w0 + ap[e + 1] * w1 + ap[e + 2] * w2 + ap[e + 3] * w3
             + ap[e + 4] * w4 + ap[e + 5] * w5 + ap[e + 6] * w6 + ap[e + 7] * w7;
    }
    for (; e < end; e++) acc += ap[e] * (float)W[(size_t)esrc[e] * 1024];
    size_t o = (size_t)n * 1024 + base;
    float v = use_skip ? elu1(elu1(acc) + (float)X16[o]) : elu1(elu1(acc));
    X16[o] = (_Float16)v;
}

// ---------------- layer 3: 16-padded (head, half) tiles, 4 nodes/block, atomic out ----------
__global__ __launch_bounds__(256) void agg726_kernel(const _Float16* __restrict__ WH16,
                                                     const int* __restrict__ rowptr,
                                                     const int* __restrict__ esrc,
                                                     const float* __restrict__ ATT,
                                                     float* __restrict__ out) {
    int id = blockIdx.x;
    int tile = id & 15, nq = id >> 4;
    if (tile >= 12) return;
    int h = tile >> 1, half = tile & 1;
    int n = nq * 4 + (threadIdx.x >> 6);
    int lane = threadIdx.x & 63;
    int len = half ? 57 : 64;
    if (lane >= len) return;
    int f = half * 64 + lane;
    const _Float16* W = WH16 + h * 121 + f;     // row stride 768
    const float* ap = ATT + (size_t)h * N_EDGES;
    int start = rowptr[n], end = rowptr[n + 1];
    float acc = 0.f;
    int e = start;
    for (; e + 8 <= end; e += 8) {
        int i0 = esrc[e],     i1 = esrc[e + 1], i2 = esrc[e + 2], i3 = esrc[e + 3];
        int i4 = esrc[e + 4], i5 = esrc[e + 5], i6 = esrc[e + 6], i7 = esrc[e + 7];
        float w0 = (float)W[(size_t)i0 * 768], w1 = (float)W[(size_t)i1 * 768];
        float w2 = (float)W[(size_t)i2 * 768], w3 = (float)W[(size_t)i3 * 768];
        float w4 = (float)W[(size_t)i4 * 768], w5 = (float)W[(size_t)i5 * 768];
        float w6 = (float)W[(size_t)i6 * 768], w7 = (float)W[(size_t)i7 * 768];
        acc += ap[e] * w0 + ap[e + 1] * w1 + ap[e + 2] * w2 + ap[e + 3] * w3
             + ap[e + 4] * w4 + ap[e + 5] * w5 + ap[e + 6] * w6 + ap[e + 7] * w7;
    }
    for (; e < end; e++) acc += ap[e] * (float)W[(size_t)esrc[e] * 768];
    atomicAdd(&out[(size_t)n * 121 + f], acc);
}

__global__ void sigmoid_kernel(float* __restrict__ out, int total) {
    int i = blockIdx.x * 256 + threadIdx.x;
    if (i < total) out[i] = 1.f / (1.f + __expf(-out[i] * (1.f / 6.f)));
}

extern "C" void kernel_launch(void* const* d_in, const int* in_sizes, int n_in,
                              void* d_out, int out_size, void* d_ws, size_t ws_size,
                              hipStream_t stream) {
    const float* x  = (const float*)d_in[0];
    const int*   ei = (const int*)d_in[1];
    const float* W1 = (const float*)d_in[2];
    const float* a1 = (const float*)d_in[3];
    const float* W2 = (const float*)d_in[4];
    const float* a2 = (const float*)d_in[5];
    const float* W3 = (const float*)d_in[6];
    const float* a3 = (const float*)d_in[7];
    float* out = (float*)d_out;
    const int N = N_NODES, E = N_EDGES;
    const int* src = ei;
    const int* dst = ei + E;

    char* ws = (char*)d_ws;
    size_t off = 0;
    auto alloc = [&](size_t b) { size_t o = off; off += (b + 255) & ~(size_t)255; return o; };
    _Float16* X16  = (_Float16*)(ws + alloc((size_t)MPAD * 1024 * 2)); // x1 then x2
    _Float16* WH16 = (_Float16*)(ws + alloc((size_t)MPAD * 1024 * 2)); // per-layer Wh
    _Float16* BT16 = (_Float16*)(ws + alloc((size_t)BT_ROWS * 1024 * 2));
    _Float16* A1   = (_Float16*)(ws + alloc((size_t)MPAD * 64 * 2));
    _Float16* BT1  = (_Float16*)(ws + alloc((size_t)BT_ROWS * 64 * 2));
    float* SPRE   = (float*)(ws + alloc((size_t)12 * N * 4));
    float* ATT    = (float*)(ws + alloc((size_t)6 * E * 4));
    int*   rowptr = (int*)(ws + alloc((size_t)(N + 1) * 4));
    int*   cursor = (int*)(ws + alloc((size_t)N * 4));
    int*   counts = (int*)(ws + alloc((size_t)N * 4));
    int*   excl   = (int*)(ws + alloc((size_t)N * 4));
    int*   partial= (int*)(ws + alloc((size_t)SCAN_BLKS * 4));
    int*   esrc   = (int*)(ws + alloc((size_t)E * 4));

    // CSR by dst
    hipMemsetAsync(counts, 0, (size_t)N * 4, stream);
    hist_kernel<<<(E + 255) / 256, 256, 0, stream>>>(dst, counts, E);
    scan1_kernel<<<SCAN_BLKS, 256, 0, stream>>>(counts, excl, partial, N);
    scan2_kernel<<<1, 128, 0, stream>>>(partial);
    scan3_kernel<<<SCAN_BLKS, 256, 0, stream>>>(excl, partial, rowptr, cursor, N, E);
    scatter_kernel<<<(E + 255) / 256, 256, 0, stream>>>(src, dst, cursor, esrc, E);
    hipMemsetAsync(X16 + (size_t)N * 1024, 0, (size_t)(MPAD - N) * 1024 * 2, stream);

    // ---- layer 1: 50 -> 4x256 concat ----
    pack_x16<<<MPAD * 64 / 256, 256, 0, stream>>>(x, A1);
    pack_bt1<<<1024 * 64 / 256, 256, 0, stream>>>(W1, BT1);
    wtilde_kernel<<<dim3(64, 8), 64, 0, stream>>>(W1, a1, BT1, 50, 64, 256, 4, 1024);
    gemm_f16<<<dim3(9, 157), 256, 0, stream>>>(A1, BT1, WH16, SPRE, N, 1024, 1024, 64);
    att_kernel<<<N / 4, 256, 0, stream>>>(rowptr, esrc, SPRE, SPRE + 4 * N, ATT, N, 4);
    agg256_kernel<<<(N / 4) * 8, 256, 0, stream>>>(WH16, rowptr, esrc, ATT, X16, 0, 0);
    agg256_kernel<<<(N / 4) * 8, 256, 0, stream>>>(WH16, rowptr, esrc, ATT, X16, 0, 1);

    // ---- layer 2: 1024 -> 4x256 concat + skip ----
    pack_bt16<<<dim3(4, 1024), 256, 0, stream>>>(W2, BT16, 256, 1024);
    wtilde_kernel<<<dim3(1024, 8), 64, 0, stream>>>(W2, a2, BT16, 1024, 1024, 256, 4, 1024);
    gemm_f16<<<dim3(9, 157), 256, 0, stream>>>(X16, BT16, WH16, SPRE, N, 1024, 1024, 1024);
    att_kernel<<<N / 4, 256, 0, stream>>>(rowptr, esrc, SPRE, SPRE + 4 * N, ATT, N, 4);
    agg256_kernel<<<(N / 4) * 8, 256, 0, stream>>>(WH16, rowptr, esrc, ATT, X16, 1, 0);
    agg256_kernel<<<(N / 4) * 8, 256, 0, stream>>>(WH16, rowptr, esrc, ATT, X16, 1, 1);

    // ---- layer 3: 1024 -> 6x121, mean over heads, sigmoid ----
    pack_bt16<<<dim3(4, 768), 256, 0, stream>>>(W3, BT16, 121, 726);
    wtilde_kernel<<<dim3(1024, 12), 64, 0, stream>>>(W3, a3, BT16, 1024, 1024, 121, 6, 726);
    gemm_f16<<<dim3(6, 157), 256, 0, stream>>>(X16, BT16, WH16, SPRE, N, 726, 768, 1024);
    att_kernel<<<N / 4, 256, 0, stream>>>(rowptr, esrc, SPRE, SPRE + 6 * N, ATT, N, 6);
    hipMemsetAsync(out, 0, (size_t)N * 121 * 4, stream);
    agg726_kernel<<<(N / 4) * 16, 256, 0, stream>>>(WH16, rowptr, esrc, ATT, out);
    sigmoid_kernel<<<(N * 121 + 255) / 256, 256, 0, stream>>>(out, N * 121);
}

// Round 9
// 558.666 us; speedup vs baseline: 1.6791x; 1.6791x over previous
//
#include <hip/hip_runtime.h>
#include <cstdint>

#define N_NODES 20000
#define N_EDGES 320000
#define ALPHA 0.2f
#define GAT_EPS 1e-16f
#define MPAD 20096           // 157 * 128
#define SCAN_BLKS 80
#define BT_ROWS 1152         // 9 col-blocks * 128

typedef __attribute__((ext_vector_type(8))) _Float16 half8;
typedef __attribute__((ext_vector_type(2))) _Float16 half2t;
typedef __attribute__((ext_vector_type(4))) float f32x4;
typedef __attribute__((ext_vector_type(2))) float f32x2;

__device__ __forceinline__ float elu1(float x) { return x > 0.f ? x : __expf(x) - 1.f; }

__device__ __forceinline__ unsigned char f2fp8(float x) {
    return (unsigned char)(__builtin_amdgcn_cvt_pk_fp8_f32(x, 0.f, 0, false) & 0xff);
}
__device__ __forceinline__ float fp82f(unsigned char b) {
    return __builtin_amdgcn_cvt_f32_fp8((int)b, 0);
}

__device__ __forceinline__ void async16(const void* g, void* l) {
    __builtin_amdgcn_global_load_lds(
        (const __attribute__((address_space(1))) unsigned int*)g,
        (__attribute__((address_space(3))) unsigned int*)l, 16, 0, 0);
}

// ---------------- CSR build ----------------
__global__ void hist_kernel(const int* __restrict__ dst, int* __restrict__ counts, int E) {
    int e = blockIdx.x * blockDim.x + threadIdx.x;
    if (e < E) atomicAdd(&counts[dst[e]], 1);
}

__global__ void scan1_kernel(const int* __restrict__ counts, int* __restrict__ excl,
                             int* __restrict__ partial, int N) {
    __shared__ int sh[256];
    int t = threadIdx.x, b = blockIdx.x;
    int i = b * 256 + t;
    int v = (i < N) ? counts[i] : 0;
    sh[t] = v;
    __syncthreads();
    for (int d = 1; d < 256; d <<= 1) {
        int x = (t >= d) ? sh[t - d] : 0;
        __syncthreads();
        sh[t] += x;
        __syncthreads();
    }
    if (i < N) excl[i] = sh[t] - v;
    if (t == 255) partial[b] = sh[255];
}

__global__ void scan2_kernel(int* __restrict__ partial) {
    __shared__ int sh[128];
    int t = threadIdx.x;
    int v = (t < SCAN_BLKS) ? partial[t] : 0;
    sh[t] = v;
    __syncthreads();
    for (int d = 1; d < 128; d <<= 1) {
        int x = (t >= d) ? sh[t - d] : 0;
        __syncthreads();
        sh[t] += x;
        __syncthreads();
    }
    if (t < SCAN_BLKS) partial[t] = sh[t] - v;
}

__global__ void scan3_kernel(const int* __restrict__ excl, const int* __restrict__ partial,
                             int* __restrict__ rowptr, int* __restrict__ cursor, int N, int E) {
    int t = threadIdx.x, b = blockIdx.x;
    int i = b * 256 + t;
    if (i < N) {
        int v = excl[i] + partial[b];
        rowptr[i] = v;
        cursor[i] = v;
    }
    if (i == 0) rowptr[N] = E;
}

__global__ void scatter_kernel(const int* __restrict__ src, const int* __restrict__ dst,
                               int* __restrict__ cursor, int* __restrict__ esrc, int E) {
    int e = blockIdx.x * blockDim.x + threadIdx.x;
    if (e < E) {
        int p = atomicAdd(&cursor[dst[e]], 1);
        esrc[p] = src[e];
    }
}

// ---------------- packs ----------------
__global__ void pack_x16(const float* __restrict__ x, _Float16* __restrict__ A) {
    int idx = blockIdx.x * 256 + threadIdx.x;   // MPAD*64
    int r = idx >> 6, c = idx & 63;
    float v = (r < N_NODES && c < 50) ? x[r * 50 + c] : 0.f;
    A[idx] = (_Float16)v;
}

__global__ void pack_bt1(const float* __restrict__ W, _Float16* __restrict__ Bt) {
    int idx = blockIdx.x * 256 + threadIdx.x;   // 1024*64
    int c = idx >> 6, k = idx & 63;
    int h = c >> 8, f = c & 255;
    float v = (k < 50) ? W[((size_t)h * 50 + k) * 256 + f] : 0.f;
    Bt[idx] = (_Float16)v;
}

__global__ void pack_bt16(const float* __restrict__ W, _Float16* __restrict__ Bt,
                          int F, int Ctot) {
    int c = blockIdx.y;
    int k = blockIdx.x * blockDim.x + threadIdx.x;
    float v = 0.f;
    if (c < Ctot) {
        int h = c / F, f = c - h * F;
        v = W[(size_t)h * 1024 * F + (size_t)k * F + f];
    }
    Bt[(size_t)c * 1024 + k] = (_Float16)v;
}

// W~ cols appended at BT rows [Nfeat, Nfeat+2H); gridDim.y MUST be 2*H.
__global__ __launch_bounds__(64) void wtilde_kernel(const float* __restrict__ W,
                                                    const float* __restrict__ a,
                                                    _Float16* __restrict__ BT, int Kreal,
                                                    int Kdim, int F, int H, int Nfeat) {
    int k = blockIdx.x, j = blockIdx.y;
    if (j >= 2 * H) return;
    int lane = threadIdx.x;
    int h = j < H ? j : j - H;
    int ao = j < H ? 0 : F;
    float s = 0.f;
    if (k < Kreal) {
        const float* wp = W + ((size_t)h * Kreal + k) * F;
        const float* ap = a + (size_t)h * 2 * F + ao;
        for (int f = lane; f < F; f += 64) s += wp[f] * ap[f];
    }
#pragma unroll
    for (int off = 32; off; off >>= 1) s += __shfl_down(s, off);
    if (lane == 0) BT[(size_t)(Nfeat + j) * Kdim + k] = (_Float16)s;
}

// ---------------- fp16 MFMA GEMM -> fp8 Wh + fp32 score cols ----------------
__global__ __launch_bounds__(256) void gemm_f16(const _Float16* __restrict__ A,
                                                const _Float16* __restrict__ BT,
                                                unsigned char* __restrict__ C8,
                                                float* __restrict__ SPRE,
                                                int M, int Nfeat, int ld, int Kdim) {
    __shared__ __align__(16) _Float16 sA[128 * 64];
    __shared__ __align__(16) _Float16 sB[128 * 64];
    int t = threadIdx.x;
    int row0 = blockIdx.y * 128, col0 = blockIdx.x * 128;
    int lane = t & 63, wave = t >> 6;
    int wm = wave >> 1, wn = wave & 1;
    int fr = lane & 15;
    int fq = lane >> 4;

    const _Float16* gA = A + (size_t)row0 * Kdim;
    const _Float16* gB = BT + (size_t)col0 * Kdim;

    int sR[4], sgl[4];
#pragma unroll
    for (int i = 0; i < 4; i++) {
        int m = i * 256 + t;
        sR[i] = m >> 3;
        sgl[i] = (m & 7) ^ (sR[i] & 7);
    }

    f32x4 acc[4][4] = {};

    for (int k0 = 0; k0 < Kdim; k0 += 64) {
        __syncthreads();
#pragma unroll
        for (int i = 0; i < 4; i++) {
            const _Float16* pa = gA + (size_t)sR[i] * Kdim + k0 + sgl[i] * 8;
            const _Float16* pb = gB + (size_t)sR[i] * Kdim + k0 + sgl[i] * 8;
            async16(pa, sA + (i * 256 + t) * 8);
            async16(pb, sB + (i * 256 + t) * 8);
        }
        __syncthreads();
#pragma unroll
        for (int ks = 0; ks < 2; ks++) {
            half8 af[4], bf[4];
#pragma unroll
            for (int mt = 0; mt < 4; mt++) {
                int R = wm * 64 + mt * 16 + fr;
                int gp = (ks * 4 + fq) ^ (R & 7);
                af[mt] = *(const half8*)(sA + R * 64 + gp * 8);
            }
#pragma unroll
            for (int nt = 0; nt < 4; nt++) {
                int R = wn * 64 + nt * 16 + fr;
                int gp = (ks * 4 + fq) ^ (R & 7);
                bf[nt] = *(const half8*)(sB + R * 64 + gp * 8);
            }
#pragma unroll
            for (int mt = 0; mt < 4; mt++)
#pragma unroll
                for (int nt = 0; nt < 4; nt++)
                    acc[mt][nt] = __builtin_amdgcn_mfma_f32_16x16x32_f16(af[mt], bf[nt], acc[mt][nt], 0, 0, 0);
        }
    }

    int rbase = row0 + wm * 64 + ((lane >> 4) << 2);
    int cbase = col0 + wn * 64 + (lane & 15);
#pragma unroll
    for (int mt = 0; mt < 4; mt++)
#pragma unroll
        for (int nt = 0; nt < 4; nt++) {
            int gc = cbase + nt * 16;
            if (gc < Nfeat) {
#pragma unroll
                for (int r = 0; r < 4; r++) {
                    int gr = rbase + mt * 16 + r;
                    if (gr < M) C8[(size_t)gr * ld + gc] = f2fp8(acc[mt][nt][r]);
                }
            } else if (gc < Nfeat + 12) {
                int j = gc - Nfeat;
#pragma unroll
                for (int r = 0; r < 4; r++) {
                    int gr = rbase + mt * 16 + r;
                    if (gr < M) SPRE[(size_t)j * N_NODES + gr] = acc[mt][nt][r];
                }
            }
        }
}

// ---------------- per-edge attention weights (CSR order), 1 node/block ----------------
__global__ __launch_bounds__(64) void att_kernel(const int* __restrict__ rowptr,
                                                 const int* __restrict__ esrc,
                                                 const float* __restrict__ SS,
                                                 const float* __restrict__ SD,
                                                 float* __restrict__ ATT, int N, int H) {
    int n = blockIdx.x, lane = threadIdx.x;
    int start = rowptr[n], end = rowptr[n + 1];
    for (int h = 0; h < H; h++) {
        const float* ss = SS + (size_t)h * N;
        float sd = SD[(size_t)h * N + n];
        float* att = ATT + (size_t)h * N_EDGES;
        float m = -INFINITY;
        for (int e = start + lane; e < end; e += 64) {
            float sc = ss[esrc[e]] + sd;
            sc = sc > 0.f ? sc : ALPHA * sc;
            m = fmaxf(m, sc);
        }
#pragma unroll
        for (int off = 32; off; off >>= 1) m = fmaxf(m, __shfl_down(m, off));
        m = __shfl(m, 0);
        float psum = 0.f;
        for (int e = start + lane; e < end; e += 64) {
            float sc = ss[esrc[e]] + sd;
            sc = sc > 0.f ? sc : ALPHA * sc;
            float p = __expf(sc - m);
            psum += p;
            att[e] = p;
        }
#pragma unroll
        for (int off = 32; off; off >>= 1) psum += __shfl_down(psum, off);
        psum = __shfl(psum, 0);
        float inv = 1.f / (psum + GAT_EPS);
        for (int e = start + lane; e < end; e += 64) att[e] *= inv;
    }
}

// ---------------- aggregate Fout=256 layers: fp8 gather, one launch, N*8 grid ----------------
// block id = n*8 + tile; tile covers 128 cols (head = tile>>1, half = tile&1); lane reads 2 fp8.
__global__ __launch_bounds__(64) void agg256_kernel(const unsigned char* __restrict__ WH8,
                                                    const int* __restrict__ rowptr,
                                                    const int* __restrict__ esrc,
                                                    const float* __restrict__ ATT,
                                                    _Float16* __restrict__ X16,
                                                    int use_skip, int N) {
    int id = blockIdx.x;
    int tile = id & 7, n = id >> 3;
    int h = tile >> 1;
    int lane = threadIdx.x;
    int base = tile * 128 + lane * 2;
    int start = rowptr[n], end = rowptr[n + 1];
    const float* ap = ATT + (size_t)h * N_EDGES;
    const unsigned char* W = WH8 + base;
    float a0 = 0.f, a1 = 0.f;
    int e = start;
    for (; e + 4 <= end; e += 4) {
        int i0 = esrc[e], i1 = esrc[e + 1], i2 = esrc[e + 2], i3 = esrc[e + 3];
        float p0 = ap[e], p1 = ap[e + 1], p2 = ap[e + 2], p3 = ap[e + 3];
        unsigned short w0 = *(const unsigned short*)(W + (size_t)i0 * 1024);
        unsigned short w1 = *(const unsigned short*)(W + (size_t)i1 * 1024);
        unsigned short w2 = *(const unsigned short*)(W + (size_t)i2 * 1024);
        unsigned short w3 = *(const unsigned short*)(W + (size_t)i3 * 1024);
        f32x2 f0 = __builtin_amdgcn_cvt_pk_f32_fp8((int)w0, false);
        f32x2 f1 = __builtin_amdgcn_cvt_pk_f32_fp8((int)w1, false);
        f32x2 f2 = __builtin_amdgcn_cvt_pk_f32_fp8((int)w2, false);
        f32x2 f3 = __builtin_amdgcn_cvt_pk_f32_fp8((int)w3, false);
        a0 += p0 * f0.x + p1 * f1.x + p2 * f2.x + p3 * f3.x;
        a1 += p0 * f0.y + p1 * f1.y + p2 * f2.y + p3 * f3.y;
    }
    for (; e < end; e++) {
        unsigned short w = *(const unsigned short*)(W + (size_t)esrc[e] * 1024);
        f32x2 f = __builtin_amdgcn_cvt_pk_f32_fp8((int)w, false);
        a0 += ap[e] * f.x;
        a1 += ap[e] * f.y;
    }
    size_t o = (size_t)n * 1024 + base;
    float v0, v1;
    if (use_skip) {
        half2t sk = *(const half2t*)(X16 + o);
        v0 = elu1(elu1(a0) + (float)sk.x);
        v1 = elu1(elu1(a1) + (float)sk.y);
    } else {
        v0 = elu1(elu1(a0));
        v1 = elu1(elu1(a1));
    }
    half2t r; r.x = (_Float16)v0; r.y = (_Float16)v1;
    *(half2t*)(X16 + o) = r;
}

// ---------------- layer 3: fused all-heads fp8 gather, mean + sigmoid ----------------
__global__ __launch_bounds__(128) void agg726_kernel(const unsigned char* __restrict__ WH8,
                                                     const int* __restrict__ rowptr,
                                                     const int* __restrict__ esrc,
                                                     const float* __restrict__ ATT,
                                                     float* __restrict__ out, int N) {
    __shared__ float part[2][128];
    int t = threadIdx.x, n = blockIdx.x;
    int lane = t & 63, wv = t >> 6;
    int h0 = wv * 3;
    int start = rowptr[n], end = rowptr[n + 1];
    float acc[3][2] = {};
    for (int e = start; e < end; e++) {
        int s = esrc[e];
        float p0 = ATT[(size_t)(h0 + 0) * N_EDGES + e];
        float p1 = ATT[(size_t)(h0 + 1) * N_EDGES + e];
        float p2 = ATT[(size_t)(h0 + 2) * N_EDGES + e];
        const unsigned char* row = WH8 + (size_t)s * 768 + h0 * 121;
        acc[0][0] += p0 * fp82f(row[lane]);
        acc[1][0] += p1 * fp82f(row[121 + lane]);
        acc[2][0] += p2 * fp82f(row[242 + lane]);
        if (lane < 57) {
            acc[0][1] += p0 * fp82f(row[64 + lane]);
            acc[1][1] += p1 * fp82f(row[185 + lane]);
            acc[2][1] += p2 * fp82f(row[306 + lane]);
        }
    }
    float s0 = acc[0][0] + acc[1][0] + acc[2][0];
    float s1 = acc[0][1] + acc[1][1] + acc[2][1];
    part[wv][lane] = s0;
    if (lane < 57) part[wv][64 + lane] = s1;
    __syncthreads();
    if (t < 121) {
        float tot = (part[0][t] + part[1][t]) * (1.f / 6.f);
        out[(size_t)n * 121 + t] = 1.f / (1.f + __expf(-tot));
    }
}

extern "C" void kernel_launch(void* const* d_in, const int* in_sizes, int n_in,
                              void* d_out, int out_size, void* d_ws, size_t ws_size,
                              hipStream_t stream) {
    const float* x  = (const float*)d_in[0];
    const int*   ei = (const int*)d_in[1];
    const float* W1 = (const float*)d_in[2];
    const float* a1 = (const float*)d_in[3];
    const float* W2 = (const float*)d_in[4];
    const float* a2 = (const float*)d_in[5];
    const float* W3 = (const float*)d_in[6];
    const float* a3 = (const float*)d_in[7];
    float* out = (float*)d_out;
    const int N = N_NODES, E = N_EDGES;
    const int* src = ei;
    const int* dst = ei + E;

    char* ws = (char*)d_ws;
    size_t off = 0;
    auto alloc = [&](size_t b) { size_t o = off; off += (b + 255) & ~(size_t)255; return o; };
    _Float16* X16  = (_Float16*)(ws + alloc((size_t)MPAD * 1024 * 2));  // x1 then x2 (fp16)
    unsigned char* WH8 = (unsigned char*)(ws + alloc((size_t)MPAD * 1024)); // per-layer Wh (fp8)
    _Float16* BT16 = (_Float16*)(ws + alloc((size_t)BT_ROWS * 1024 * 2));
    _Float16* A1   = (_Float16*)(ws + alloc((size_t)MPAD * 64 * 2));
    _Float16* BT1  = (_Float16*)(ws + alloc((size_t)BT_ROWS * 64 * 2));
    float* SPRE   = (float*)(ws + alloc((size_t)12 * N * 4));
    float* ATT    = (float*)(ws + alloc((size_t)6 * E * 4));
    int*   rowptr = (int*)(ws + alloc((size_t)(N + 1) * 4));
    int*   cursor = (int*)(ws + alloc((size_t)N * 4));
    int*   counts = (int*)(ws + alloc((size_t)N * 4));
    int*   excl   = (int*)(ws + alloc((size_t)N * 4));
    int*   partial= (int*)(ws + alloc((size_t)SCAN_BLKS * 4));
    int*   esrc   = (int*)(ws + alloc((size_t)E * 4));

    // CSR by dst
    hipMemsetAsync(counts, 0, (size_t)N * 4, stream);
    hist_kernel<<<(E + 255) / 256, 256, 0, stream>>>(dst, counts, E);
    scan1_kernel<<<SCAN_BLKS, 256, 0, stream>>>(counts, excl, partial, N);
    scan2_kernel<<<1, 128, 0, stream>>>(partial);
    scan3_kernel<<<SCAN_BLKS, 256, 0, stream>>>(excl, partial, rowptr, cursor, N, E);
    scatter_kernel<<<(E + 255) / 256, 256, 0, stream>>>(src, dst, cursor, esrc, E);
    hipMemsetAsync(X16 + (size_t)N * 1024, 0, (size_t)(MPAD - N) * 1024 * 2, stream);

    // ---- layer 1: 50 -> 4x256 concat ----
    pack_x16<<<MPAD * 64 / 256, 256, 0, stream>>>(x, A1);
    pack_bt1<<<1024 * 64 / 256, 256, 0, stream>>>(W1, BT1);
    wtilde_kernel<<<dim3(64, 8), 64, 0, stream>>>(W1, a1, BT1, 50, 64, 256, 4, 1024);
    gemm_f16<<<dim3(9, 157), 256, 0, stream>>>(A1, BT1, WH8, SPRE, N, 1024, 1024, 64);
    att_kernel<<<N, 64, 0, stream>>>(rowptr, esrc, SPRE, SPRE + 4 * N, ATT, N, 4);
    agg256_kernel<<<N * 8, 64, 0, stream>>>(WH8, rowptr, esrc, ATT, X16, 0, N);

    // ---- layer 2: 1024 -> 4x256 concat + skip ----
    pack_bt16<<<dim3(4, 1024), 256, 0, stream>>>(W2, BT16, 256, 1024);
    wtilde_kernel<<<dim3(1024, 8), 64, 0, stream>>>(W2, a2, BT16, 1024, 1024, 256, 4, 1024);
    gemm_f16<<<dim3(9, 157), 256, 0, stream>>>(X16, BT16, WH8, SPRE, N, 1024, 1024, 1024);
    att_kernel<<<N, 64, 0, stream>>>(rowptr, esrc, SPRE, SPRE + 4 * N, ATT, N, 4);
    agg256_kernel<<<N * 8, 64, 0, stream>>>(WH8, rowptr, esrc, ATT, X16, 1, N);

    // ---- layer 3: 1024 -> 6x121, mean over heads, sigmoid ----
    pack_bt16<<<dim3(4, 768), 256, 0, stream>>>(W3, BT16, 121, 726);
    wtilde_kernel<<<dim3(1024, 12), 64, 0, stream>>>(W3, a3, BT16, 1024, 1024, 121, 6, 726);
    gemm_f16<<<dim3(6, 157), 256, 0, stream>>>(X16, BT16, WH8, SPRE, N, 726, 768, 1024);
    att_kernel<<<N, 64, 0, stream>>>(rowptr, esrc, SPRE, SPRE + 6 * N, ATT, N, 6);
    agg726_kernel<<<N, 128, 0, stream>>>(WH8, rowptr, esrc, ATT, out, N);
}

// Round 10
// 534.669 us; speedup vs baseline: 1.7544x; 1.0449x over previous
//
#include <hip/hip_runtime.h>
#include <cstdint>

#define N_NODES 20000
#define N_EDGES 320000
#define ALPHA 0.2f
#define GAT_EPS 1e-16f
#define MPAD 20096           // 157 * 128
#define RBLK 157
#define RHI 20               // ceil(157/8)
#define SCAN_BLKS 80
#define BT_ROWS 1152         // 9 col-blocks * 128

typedef __attribute__((ext_vector_type(8))) _Float16 half8;
typedef __attribute__((ext_vector_type(2))) _Float16 half2t;
typedef __attribute__((ext_vector_type(4))) float f32x4;
typedef __attribute__((ext_vector_type(2))) float f32x2;

__device__ __forceinline__ float elu1(float x) { return x > 0.f ? x : __expf(x) - 1.f; }

__device__ __forceinline__ unsigned char f2fp8(float x) {
    return (unsigned char)(__builtin_amdgcn_cvt_pk_fp8_f32(x, 0.f, 0, false) & 0xff);
}
__device__ __forceinline__ float fp82f(unsigned char b) {
    return __builtin_amdgcn_cvt_f32_fp8((int)b, 0);
}

__device__ __forceinline__ void async16(const void* g, void* l) {
    __builtin_amdgcn_global_load_lds(
        (const __attribute__((address_space(1))) unsigned int*)g,
        (__attribute__((address_space(3))) unsigned int*)l, 16, 0, 0);
}

// ---------------- CSR build ----------------
__global__ void hist_kernel(const int* __restrict__ dst, int* __restrict__ counts, int E) {
    int e = blockIdx.x * blockDim.x + threadIdx.x;
    if (e < E) atomicAdd(&counts[dst[e]], 1);
}

__global__ void scan1_kernel(const int* __restrict__ counts, int* __restrict__ excl,
                             int* __restrict__ partial, int N) {
    __shared__ int sh[256];
    int t = threadIdx.x, b = blockIdx.x;
    int i = b * 256 + t;
    int v = (i < N) ? counts[i] : 0;
    sh[t] = v;
    __syncthreads();
    for (int d = 1; d < 256; d <<= 1) {
        int x = (t >= d) ? sh[t - d] : 0;
        __syncthreads();
        sh[t] += x;
        __syncthreads();
    }
    if (i < N) excl[i] = sh[t] - v;
    if (t == 255) partial[b] = sh[255];
}

__global__ void scan2_kernel(int* __restrict__ partial) {
    __shared__ int sh[128];
    int t = threadIdx.x;
    int v = (t < SCAN_BLKS) ? partial[t] : 0;
    sh[t] = v;
    __syncthreads();
    for (int d = 1; d < 128; d <<= 1) {
        int x = (t >= d) ? sh[t - d] : 0;
        __syncthreads();
        sh[t] += x;
        __syncthreads();
    }
    if (t < SCAN_BLKS) partial[t] = sh[t] - v;
}

__global__ void scan3_kernel(const int* __restrict__ excl, const int* __restrict__ partial,
                             int* __restrict__ rowptr, int* __restrict__ cursor, int N, int E) {
    int t = threadIdx.x, b = blockIdx.x;
    int i = b * 256 + t;
    if (i < N) {
        int v = excl[i] + partial[b];
        rowptr[i] = v;
        cursor[i] = v;
    }
    if (i == 0) rowptr[N] = E;
}

__global__ void scatter_kernel(const int* __restrict__ src, const int* __restrict__ dst,
                               int* __restrict__ cursor, int* __restrict__ esrc, int E) {
    int e = blockIdx.x * blockDim.x + threadIdx.x;
    if (e < E) {
        int p = atomicAdd(&cursor[dst[e]], 1);
        esrc[p] = src[e];
    }
}

// ---------------- packs ----------------
__global__ void pack_x16(const float* __restrict__ x, _Float16* __restrict__ A) {
    int idx = blockIdx.x * 256 + threadIdx.x;   // MPAD*64
    int r = idx >> 6, c = idx & 63;
    float v = (r < N_NODES && c < 50) ? x[r * 50 + c] : 0.f;
    A[idx] = (_Float16)v;
}

__global__ void pack_bt1(const float* __restrict__ W, _Float16* __restrict__ Bt) {
    int idx = blockIdx.x * 256 + threadIdx.x;   // 1024*64
    int c = idx >> 6, k = idx & 63;
    int h = c >> 8, f = c & 255;
    float v = (k < 50) ? W[((size_t)h * 50 + k) * 256 + f] : 0.f;
    Bt[idx] = (_Float16)v;
}

__global__ void pack_bt16(const float* __restrict__ W, _Float16* __restrict__ Bt,
                          int F, int Ctot) {
    int c = blockIdx.y;
    int k = blockIdx.x * blockDim.x + threadIdx.x;
    float v = 0.f;
    if (c < Ctot) {
        int h = c / F, f = c - h * F;
        v = W[(size_t)h * 1024 * F + (size_t)k * F + f];
    }
    Bt[(size_t)c * 1024 + k] = (_Float16)v;
}

// W~ cols appended at BT rows [Nfeat, Nfeat+2H); gridDim.y MUST be 2*H.
__global__ __launch_bounds__(64) void wtilde_kernel(const float* __restrict__ W,
                                                    const float* __restrict__ a,
                                                    _Float16* __restrict__ BT, int Kreal,
                                                    int Kdim, int F, int H, int Nfeat) {
    int k = blockIdx.x, j = blockIdx.y;
    if (j >= 2 * H) return;
    int lane = threadIdx.x;
    int h = j < H ? j : j - H;
    int ao = j < H ? 0 : F;
    float s = 0.f;
    if (k < Kreal) {
        const float* wp = W + ((size_t)h * Kreal + k) * F;
        const float* ap = a + (size_t)h * 2 * F + ao;
        for (int f = lane; f < F; f += 64) s += wp[f] * ap[f];
    }
#pragma unroll
    for (int off = 32; off; off >>= 1) s += __shfl_down(s, off);
    if (lane == 0) BT[(size_t)(Nfeat + j) * Kdim + k] = (_Float16)s;
}

// ---------------- fp16 MFMA GEMM -> fp8 Wh + fp32 score cols; XCD-swizzled 1D grid ----------
// id = (r&7) + 8*((r>>3)*Cblk + c)  => all col-blocks of row-block r share id%8 (same XCD
// under round-robin dispatch) so each XCD streams its A row-tiles once and reuses in L2.
__global__ __launch_bounds__(256) void gemm_f16(const _Float16* __restrict__ A,
                                                const _Float16* __restrict__ BT,
                                                unsigned char* __restrict__ C8,
                                                float* __restrict__ SPRE,
                                                int M, int Nfeat, int ld, int Kdim, int Cblk) {
    int id = blockIdx.x;
    int xm = id & 7, q = id >> 3;
    int cb = q % Cblk, rh = q / Cblk;
    int rb = rh * 8 + xm;
    if (rb >= RBLK) return;
    __shared__ __align__(16) _Float16 sA[128 * 64];
    __shared__ __align__(16) _Float16 sB[128 * 64];
    int t = threadIdx.x;
    int row0 = rb * 128, col0 = cb * 128;
    int lane = t & 63, wave = t >> 6;
    int wm = wave >> 1, wn = wave & 1;
    int fr = lane & 15;
    int fq = lane >> 4;

    const _Float16* gA = A + (size_t)row0 * Kdim;
    const _Float16* gB = BT + (size_t)col0 * Kdim;

    int sR[4], sgl[4];
#pragma unroll
    for (int i = 0; i < 4; i++) {
        int m = i * 256 + t;
        sR[i] = m >> 3;
        sgl[i] = (m & 7) ^ (sR[i] & 7);
    }

    f32x4 acc[4][4] = {};

    for (int k0 = 0; k0 < Kdim; k0 += 64) {
        __syncthreads();
#pragma unroll
        for (int i = 0; i < 4; i++) {
            const _Float16* pa = gA + (size_t)sR[i] * Kdim + k0 + sgl[i] * 8;
            const _Float16* pb = gB + (size_t)sR[i] * Kdim + k0 + sgl[i] * 8;
            async16(pa, sA + (i * 256 + t) * 8);
            async16(pb, sB + (i * 256 + t) * 8);
        }
        __syncthreads();
#pragma unroll
        for (int ks = 0; ks < 2; ks++) {
            half8 af[4], bf[4];
#pragma unroll
            for (int mt = 0; mt < 4; mt++) {
                int R = wm * 64 + mt * 16 + fr;
                int gp = (ks * 4 + fq) ^ (R & 7);
                af[mt] = *(const half8*)(sA + R * 64 + gp * 8);
            }
#pragma unroll
            for (int nt = 0; nt < 4; nt++) {
                int R = wn * 64 + nt * 16 + fr;
                int gp = (ks * 4 + fq) ^ (R & 7);
                bf[nt] = *(const half8*)(sB + R * 64 + gp * 8);
            }
#pragma unroll
            for (int mt = 0; mt < 4; mt++)
#pragma unroll
                for (int nt = 0; nt < 4; nt++)
                    acc[mt][nt] = __builtin_amdgcn_mfma_f32_16x16x32_f16(af[mt], bf[nt], acc[mt][nt], 0, 0, 0);
        }
    }

    int rbase = row0 + wm * 64 + ((lane >> 4) << 2);
    int cbase = col0 + wn * 64 + (lane & 15);
#pragma unroll
    for (int mt = 0; mt < 4; mt++)
#pragma unroll
        for (int nt = 0; nt < 4; nt++) {
            int gc = cbase + nt * 16;
            if (gc < Nfeat) {
#pragma unroll
                for (int r = 0; r < 4; r++) {
                    int gr = rbase + mt * 16 + r;
                    if (gr < M) C8[(size_t)gr * ld + gc] = f2fp8(acc[mt][nt][r]);
                }
            } else if (gc < Nfeat + 12) {
                int j = gc - Nfeat;
#pragma unroll
                for (int r = 0; r < 4; r++) {
                    int gr = rbase + mt * 16 + r;
                    if (gr < M) SPRE[(size_t)j * N_NODES + gr] = acc[mt][nt][r];
                }
            }
        }
}

// ---------------- per-edge attention: online softmax, 2 passes, head-per-wave ----------------
__global__ void att_kernel(const int* __restrict__ rowptr,
                           const int* __restrict__ esrc,
                           const float* __restrict__ SS,
                           const float* __restrict__ SD,
                           float* __restrict__ ATT, int N, int H) {
    int n = blockIdx.x;
    int h = threadIdx.x >> 6;
    int lane = threadIdx.x & 63;
    if (h >= H) return;
    int start = rowptr[n], end = rowptr[n + 1];
    const float* ss = SS + (size_t)h * N;
    float sd = SD[(size_t)h * N + n];
    float* att = ATT + (size_t)h * N_EDGES;
    float m = -1e30f, s = 0.f;
    for (int e = start + lane; e < end; e += 64) {
        float sc = ss[esrc[e]] + sd;
        sc = sc > 0.f ? sc : ALPHA * sc;
        float mn = fmaxf(m, sc);
        s = s * __expf(m - mn) + __expf(sc - mn);
        m = mn;
    }
#pragma unroll
    for (int off = 1; off < 64; off <<= 1) {
        float mo = __shfl_xor(m, off);
        float so = __shfl_xor(s, off);
        float mn = fmaxf(m, mo);
        s = s * __expf(m - mn) + so * __expf(mo - mn);
        m = mn;
    }
    float inv = 1.f / (s + GAT_EPS);
    for (int e = start + lane; e < end; e += 64) {
        float sc = ss[esrc[e]] + sd;
        sc = sc > 0.f ? sc : ALPHA * sc;
        att[e] = __expf(sc - m) * inv;
    }
}

// ---------------- aggregate Fout=256 layers: fp8 gather, one launch, N*8 grid ----------------
__global__ __launch_bounds__(64) void agg256_kernel(const unsigned char* __restrict__ WH8,
                                                    const int* __restrict__ rowptr,
                                                    const int* __restrict__ esrc,
                                                    const float* __restrict__ ATT,
                                                    _Float16* __restrict__ X16,
                                                    int use_skip, int N) {
    int id = blockIdx.x;
    int tile = id & 7, n = id >> 3;
    int h = tile >> 1;
    int lane = threadIdx.x;
    int base = tile * 128 + lane * 2;
    int start = rowptr[n], end = rowptr[n + 1];
    const float* ap = ATT + (size_t)h * N_EDGES;
    const unsigned char* W = WH8 + base;
    float a0 = 0.f, a1 = 0.f;
    int e = start;
    for (; e + 4 <= end; e += 4) {
        int i0 = esrc[e], i1 = esrc[e + 1], i2 = esrc[e + 2], i3 = esrc[e + 3];
        float p0 = ap[e], p1 = ap[e + 1], p2 = ap[e + 2], p3 = ap[e + 3];
        unsigned short w0 = *(const unsigned short*)(W + (size_t)i0 * 1024);
        unsigned short w1 = *(const unsigned short*)(W + (size_t)i1 * 1024);
        unsigned short w2 = *(const unsigned short*)(W + (size_t)i2 * 1024);
        unsigned short w3 = *(const unsigned short*)(W + (size_t)i3 * 1024);
        f32x2 f0 = __builtin_amdgcn_cvt_pk_f32_fp8((int)w0, false);
        f32x2 f1 = __builtin_amdgcn_cvt_pk_f32_fp8((int)w1, false);
        f32x2 f2 = __builtin_amdgcn_cvt_pk_f32_fp8((int)w2, false);
        f32x2 f3 = __builtin_amdgcn_cvt_pk_f32_fp8((int)w3, false);
        a0 += p0 * f0.x + p1 * f1.x + p2 * f2.x + p3 * f3.x;
        a1 += p0 * f0.y + p1 * f1.y + p2 * f2.y + p3 * f3.y;
    }
    for (; e < end; e++) {
        unsigned short w = *(const unsigned short*)(W + (size_t)esrc[e] * 1024);
        f32x2 f = __builtin_amdgcn_cvt_pk_f32_fp8((int)w, false);
        a0 += ap[e] * f.x;
        a1 += ap[e] * f.y;
    }
    size_t o = (size_t)n * 1024 + base;
    float v0, v1;
    if (use_skip) {
        half2t sk = *(const half2t*)(X16 + o);
        v0 = elu1(elu1(a0) + (float)sk.x);
        v1 = elu1(elu1(a1) + (float)sk.y);
    } else {
        v0 = elu1(elu1(a0));
        v1 = elu1(elu1(a1));
    }
    half2t r; r.x = (_Float16)v0; r.y = (_Float16)v1;
    *(half2t*)(X16 + o) = r;
}

// ---------------- layer 3: fused all-heads fp8 gather, mean + sigmoid ----------------
__global__ __launch_bounds__(128) void agg726_kernel(const unsigned char* __restrict__ WH8,
                                                     const int* __restrict__ rowptr,
                                                     const int* __restrict__ esrc,
                                                     const float* __restrict__ ATT,
                                                     float* __restrict__ out, int N) {
    __shared__ float part[2][128];
    int t = threadIdx.x, n = blockIdx.x;
    int lane = t & 63, wv = t >> 6;
    int h0 = wv * 3;
    int start = rowptr[n], end = rowptr[n + 1];
    float acc[3][2] = {};
    for (int e = start; e < end; e++) {
        int s = esrc[e];
        float p0 = ATT[(size_t)(h0 + 0) * N_EDGES + e];
        float p1 = ATT[(size_t)(h0 + 1) * N_EDGES + e];
        float p2 = ATT[(size_t)(h0 + 2) * N_EDGES + e];
        const unsigned char* row = WH8 + (size_t)s * 768 + h0 * 121;
        acc[0][0] += p0 * fp82f(row[lane]);
        acc[1][0] += p1 * fp82f(row[121 + lane]);
        acc[2][0] += p2 * fp82f(row[242 + lane]);
        if (lane < 57) {
            acc[0][1] += p0 * fp82f(row[64 + lane]);
            acc[1][1] += p1 * fp82f(row[185 + lane]);
            acc[2][1] += p2 * fp82f(row[306 + lane]);
        }
    }
    float s0 = acc[0][0] + acc[1][0] + acc[2][0];
    float s1 = acc[0][1] + acc[1][1] + acc[2][1];
    part[wv][lane] = s0;
    if (lane < 57) part[wv][64 + lane] = s1;
    __syncthreads();
    if (t < 121) {
        float tot = (part[0][t] + part[1][t]) * (1.f / 6.f);
        out[(size_t)n * 121 + t] = 1.f / (1.f + __expf(-tot));
    }
}

extern "C" void kernel_launch(void* const* d_in, const int* in_sizes, int n_in,
                              void* d_out, int out_size, void* d_ws, size_t ws_size,
                              hipStream_t stream) {
    const float* x  = (const float*)d_in[0];
    const int*   ei = (const int*)d_in[1];
    const float* W1 = (const float*)d_in[2];
    const float* a1 = (const float*)d_in[3];
    const float* W2 = (const float*)d_in[4];
    const float* a2 = (const float*)d_in[5];
    const float* W3 = (const float*)d_in[6];
    const float* a3 = (const float*)d_in[7];
    float* out = (float*)d_out;
    const int N = N_NODES, E = N_EDGES;
    const int* src = ei;
    const int* dst = ei + E;

    char* ws = (char*)d_ws;
    size_t off = 0;
    auto alloc = [&](size_t b) { size_t o = off; off += (b + 255) & ~(size_t)255; return o; };
    _Float16* X16  = (_Float16*)(ws + alloc((size_t)MPAD * 1024 * 2));  // x1 then x2 (fp16)
    unsigned char* WH8 = (unsigned char*)(ws + alloc((size_t)MPAD * 1024)); // per-layer Wh (fp8)
    _Float16* BT16 = (_Float16*)(ws + alloc((size_t)BT_ROWS * 1024 * 2));
    _Float16* A1   = (_Float16*)(ws + alloc((size_t)MPAD * 64 * 2));
    _Float16* BT1  = (_Float16*)(ws + alloc((size_t)BT_ROWS * 64 * 2));
    float* SPRE   = (float*)(ws + alloc((size_t)12 * N * 4));
    float* ATT    = (float*)(ws + alloc((size_t)6 * E * 4));
    int*   rowptr = (int*)(ws + alloc((size_t)(N + 1) * 4));
    int*   cursor = (int*)(ws + alloc((size_t)N * 4));
    int*   counts = (int*)(ws + alloc((size_t)N * 4));
    int*   excl   = (int*)(ws + alloc((size_t)N * 4));
    int*   partial= (int*)(ws + alloc((size_t)SCAN_BLKS * 4));
    int*   esrc   = (int*)(ws + alloc((size_t)E * 4));

    // CSR by dst
    hipMemsetAsync(counts, 0, (size_t)N * 4, stream);
    hist_kernel<<<(E + 255) / 256, 256, 0, stream>>>(dst, counts, E);
    scan1_kernel<<<SCAN_BLKS, 256, 0, stream>>>(counts, excl, partial, N);
    scan2_kernel<<<1, 128, 0, stream>>>(partial);
    scan3_kernel<<<SCAN_BLKS, 256, 0, stream>>>(excl, partial, rowptr, cursor, N, E);
    scatter_kernel<<<(E + 255) / 256, 256, 0, stream>>>(src, dst, cursor, esrc, E);
    hipMemsetAsync(X16 + (size_t)N * 1024, 0, (size_t)(MPAD - N) * 1024 * 2, stream);

    // ---- layer 1: 50 -> 4x256 concat ----
    pack_x16<<<MPAD * 64 / 256, 256, 0, stream>>>(x, A1);
    pack_bt1<<<1024 * 64 / 256, 256, 0, stream>>>(W1, BT1);
    wtilde_kernel<<<dim3(64, 8), 64, 0, stream>>>(W1, a1, BT1, 50, 64, 256, 4, 1024);
    gemm_f16<<<8 * RHI * 9, 256, 0, stream>>>(A1, BT1, WH8, SPRE, N, 1024, 1024, 64, 9);
    att_kernel<<<N, 256, 0, stream>>>(rowptr, esrc, SPRE, SPRE + 4 * N, ATT, N, 4);
    agg256_kernel<<<N * 8, 64, 0, stream>>>(WH8, rowptr, esrc, ATT, X16, 0, N);

    // ---- layer 2: 1024 -> 4x256 concat + skip ----
    pack_bt16<<<dim3(4, 1024), 256, 0, stream>>>(W2, BT16, 256, 1024);
    wtilde_kernel<<<dim3(1024, 8), 64, 0, stream>>>(W2, a2, BT16, 1024, 1024, 256, 4, 1024);
    gemm_f16<<<8 * RHI * 9, 256, 0, stream>>>(X16, BT16, WH8, SPRE, N, 1024, 1024, 1024, 9);
    att_kernel<<<N, 256, 0, stream>>>(rowptr, esrc, SPRE, SPRE + 4 * N, ATT, N, 4);
    agg256_kernel<<<N * 8, 64, 0, stream>>>(WH8, rowptr, esrc, ATT, X16, 1, N);

    // ---- layer 3: 1024 -> 6x121, mean over heads, sigmoid ----
    pack_bt16<<<dim3(4, 768), 256, 0, stream>>>(W3, BT16, 121, 726);
    wtilde_kernel<<<dim3(1024, 12), 64, 0, stream>>>(W3, a3, BT16, 1024, 1024, 121, 6, 726);
    gemm_f16<<<8 * RHI * 6, 256, 0, stream>>>(X16, BT16, WH8, SPRE, N, 726, 768, 1024, 6);
    att_kernel<<<N, 384, 0, stream>>>(rowptr, esrc, SPRE, SPRE + 6 * N, ATT, N, 6);
    agg726_kernel<<<N, 128, 0, stream>>>(WH8, rowptr, esrc, ATT, out, N);
}

// Round 11
// 523.890 us; speedup vs baseline: 1.7905x; 1.0206x over previous
//
#include <hip/hip_runtime.h>
#include <cstdint>

#define N_NODES 20000
#define N_EDGES 320000
#define ALPHA 0.2f
#define GAT_EPS 1e-16f
#define MPAD 20096           // 157 * 128
#define RBLK 157
#define RHI 20               // ceil(157/8)
#define SCAN_BLKS 80
#define BT_ROWS 1152         // 9 col-blocks * 128

typedef __attribute__((ext_vector_type(8))) _Float16 half8;
typedef __attribute__((ext_vector_type(2))) _Float16 half2t;
typedef __attribute__((ext_vector_type(16))) float f32x16;
typedef __attribute__((ext_vector_type(2))) float f32x2;

__device__ __forceinline__ float elu1(float x) { return x > 0.f ? x : __expf(x) - 1.f; }

__device__ __forceinline__ unsigned char f2fp8(float x) {
    return (unsigned char)(__builtin_amdgcn_cvt_pk_fp8_f32(x, 0.f, 0, false) & 0xff);
}
__device__ __forceinline__ float fp82f(unsigned char b) {
    return __builtin_amdgcn_cvt_f32_fp8((int)b, 0);
}

__device__ __forceinline__ void async16(const void* g, void* l) {
    __builtin_amdgcn_global_load_lds(
        (const __attribute__((address_space(1))) unsigned int*)g,
        (__attribute__((address_space(3))) unsigned int*)l, 16, 0, 0);
}

// ---------------- CSR build ----------------
__global__ void hist_kernel(const int* __restrict__ dst, int* __restrict__ counts, int E) {
    int e = blockIdx.x * blockDim.x + threadIdx.x;
    if (e < E) atomicAdd(&counts[dst[e]], 1);
}

__global__ void scan1_kernel(const int* __restrict__ counts, int* __restrict__ excl,
                             int* __restrict__ partial, int N) {
    __shared__ int sh[256];
    int t = threadIdx.x, b = blockIdx.x;
    int i = b * 256 + t;
    int v = (i < N) ? counts[i] : 0;
    sh[t] = v;
    __syncthreads();
    for (int d = 1; d < 256; d <<= 1) {
        int x = (t >= d) ? sh[t - d] : 0;
        __syncthreads();
        sh[t] += x;
        __syncthreads();
    }
    if (i < N) excl[i] = sh[t] - v;
    if (t == 255) partial[b] = sh[255];
}

__global__ void scan2_kernel(int* __restrict__ partial) {
    __shared__ int sh[128];
    int t = threadIdx.x;
    int v = (t < SCAN_BLKS) ? partial[t] : 0;
    sh[t] = v;
    __syncthreads();
    for (int d = 1; d < 128; d <<= 1) {
        int x = (t >= d) ? sh[t - d] : 0;
        __syncthreads();
        sh[t] += x;
        __syncthreads();
    }
    if (t < SCAN_BLKS) partial[t] = sh[t] - v;
}

__global__ void scan3_kernel(const int* __restrict__ excl, const int* __restrict__ partial,
                             int* __restrict__ rowptr, int* __restrict__ cursor, int N, int E) {
    int t = threadIdx.x, b = blockIdx.x;
    int i = b * 256 + t;
    if (i < N) {
        int v = excl[i] + partial[b];
        rowptr[i] = v;
        cursor[i] = v;
    }
    if (i == 0) rowptr[N] = E;
}

__global__ void scatter_kernel(const int* __restrict__ src, const int* __restrict__ dst,
                               int* __restrict__ cursor, int* __restrict__ esrc, int E) {
    int e = blockIdx.x * blockDim.x + threadIdx.x;
    if (e < E) {
        int p = atomicAdd(&cursor[dst[e]], 1);
        esrc[p] = src[e];
    }
}

// ---------------- packs ----------------
__global__ void pack_x16(const float* __restrict__ x, _Float16* __restrict__ A) {
    int idx = blockIdx.x * 256 + threadIdx.x;   // MPAD*64
    int r = idx >> 6, c = idx & 63;
    float v = (r < N_NODES && c < 50) ? x[r * 50 + c] : 0.f;
    A[idx] = (_Float16)v;
}

__global__ void pack_bt1(const float* __restrict__ W, _Float16* __restrict__ Bt) {
    int idx = blockIdx.x * 256 + threadIdx.x;   // 1024*64
    int c = idx >> 6, k = idx & 63;
    int h = c >> 8, f = c & 255;
    float v = (k < 50) ? W[((size_t)h * 50 + k) * 256 + f] : 0.f;
    Bt[idx] = (_Float16)v;
}

__global__ void pack_bt16(const float* __restrict__ W, _Float16* __restrict__ Bt,
                          int F, int Ctot) {
    int c = blockIdx.y;
    int k = blockIdx.x * blockDim.x + threadIdx.x;
    float v = 0.f;
    if (c < Ctot) {
        int h = c / F, f = c - h * F;
        v = W[(size_t)h * 1024 * F + (size_t)k * F + f];
    }
    Bt[(size_t)c * 1024 + k] = (_Float16)v;
}

// W~ cols appended at BT rows [Nfeat, Nfeat+2H); gridDim.y MUST be 2*H.
__global__ __launch_bounds__(64) void wtilde_kernel(const float* __restrict__ W,
                                                    const float* __restrict__ a,
                                                    _Float16* __restrict__ BT, int Kreal,
                                                    int Kdim, int F, int H, int Nfeat) {
    int k = blockIdx.x, j = blockIdx.y;
    if (j >= 2 * H) return;
    int lane = threadIdx.x;
    int h = j < H ? j : j - H;
    int ao = j < H ? 0 : F;
    float s = 0.f;
    if (k < Kreal) {
        const float* wp = W + ((size_t)h * Kreal + k) * F;
        const float* ap = a + (size_t)h * 2 * F + ao;
        for (int f = lane; f < F; f += 64) s += wp[f] * ap[f];
    }
#pragma unroll
    for (int off = 32; off; off >>= 1) s += __shfl_down(s, off);
    if (lane == 0) BT[(size_t)(Nfeat + j) * Kdim + k] = (_Float16)s;
}

// ---------------- fp16 MFMA GEMM (32x32x16) -> fp8 Wh + fp32 score cols; XCD-swizzled ------
// id = (r&7) + 8*((r>>3)*Cblk + c) : col-blocks of row-block r share id%8 (same XCD).
// Wave tile 64x64 = 2x2 of 32x32x16 MFMA: half the MFMA instruction count of 16x16x32
// for the same FLOPs/LDS-bytes (R10 showed the K-loop is issue-bound, not fetch-bound).
__global__ __launch_bounds__(256) void gemm_f16(const _Float16* __restrict__ A,
                                                const _Float16* __restrict__ BT,
                                                unsigned char* __restrict__ C8,
                                                float* __restrict__ SPRE,
                                                int M, int Nfeat, int ld, int Kdim, int Cblk) {
    int id = blockIdx.x;
    int xm = id & 7, q = id >> 3;
    int cb = q % Cblk, rh = q / Cblk;
    int rb = rh * 8 + xm;
    if (rb >= RBLK) return;
    __shared__ __align__(16) _Float16 sA[128 * 64];
    __shared__ __align__(16) _Float16 sB[128 * 64];
    int t = threadIdx.x;
    int row0 = rb * 128, col0 = cb * 128;
    int lane = t & 63, wave = t >> 6;
    int wm = wave >> 1, wn = wave & 1;
    int l31 = lane & 31;
    int lhi = lane >> 5;                 // 0/1: k-half within 16-group

    const _Float16* gA = A + (size_t)row0 * Kdim;
    const _Float16* gB = BT + (size_t)col0 * Kdim;

    int sR[4], sgl[4];
#pragma unroll
    for (int i = 0; i < 4; i++) {
        int m = i * 256 + t;
        sR[i] = m >> 3;
        sgl[i] = (m & 7) ^ (sR[i] & 7);
    }

    f32x16 acc[2][2] = {};

    for (int k0 = 0; k0 < Kdim; k0 += 64) {
        __syncthreads();
#pragma unroll
        for (int i = 0; i < 4; i++) {
            const _Float16* pa = gA + (size_t)sR[i] * Kdim + k0 + sgl[i] * 8;
            const _Float16* pb = gB + (size_t)sR[i] * Kdim + k0 + sgl[i] * 8;
            async16(pa, sA + (i * 256 + t) * 8);
            async16(pb, sB + (i * 256 + t) * 8);
        }
        __syncthreads();
#pragma unroll
        for (int kk = 0; kk < 4; kk++) {
            int g = kk * 2 + lhi;        // 16B-group within 64-half row
            half8 af[2], bf[2];
#pragma unroll
            for (int mt = 0; mt < 2; mt++) {
                int R = wm * 64 + mt * 32 + l31;
                int gp = g ^ (R & 7);
                af[mt] = *(const half8*)(sA + R * 64 + gp * 8);
            }
#pragma unroll
            for (int nt = 0; nt < 2; nt++) {
                int R = wn * 64 + nt * 32 + l31;
                int gp = g ^ (R & 7);
                bf[nt] = *(const half8*)(sB + R * 64 + gp * 8);
            }
#pragma unroll
            for (int mt = 0; mt < 2; mt++)
#pragma unroll
                for (int nt = 0; nt < 2; nt++)
                    acc[mt][nt] = __builtin_amdgcn_mfma_f32_32x32x16_f16(af[mt], bf[nt], acc[mt][nt], 0, 0, 0);
        }
    }

    // C/D layout (32x32): col = lane&31, row = (r&3) + 8*(r>>2) + 4*(lane>>5)
    int cb32 = col0 + wn * 64 + l31;
    int rb32 = row0 + wm * 64 + 4 * lhi;
#pragma unroll
    for (int mt = 0; mt < 2; mt++)
#pragma unroll
        for (int nt = 0; nt < 2; nt++) {
            int gc = cb32 + nt * 32;
            if (gc < Nfeat) {
#pragma unroll
                for (int r = 0; r < 16; r++) {
                    int gr = rb32 + mt * 32 + (r & 3) + 8 * (r >> 2);
                    if (gr < M) C8[(size_t)gr * ld + gc] = f2fp8(acc[mt][nt][r]);
                }
            } else if (gc < Nfeat + 12) {
                int j = gc - Nfeat;
#pragma unroll
                for (int r = 0; r < 16; r++) {
                    int gr = rb32 + mt * 32 + (r & 3) + 8 * (r >> 2);
                    if (gr < M) SPRE[(size_t)j * N_NODES + gr] = acc[mt][nt][r];
                }
            }
        }
}

// ---------------- per-edge attention: online softmax, 2 passes, head-per-wave ----------------
__global__ void att_kernel(const int* __restrict__ rowptr,
                           const int* __restrict__ esrc,
                           const float* __restrict__ SS,
                           const float* __restrict__ SD,
                           float* __restrict__ ATT, int N, int H) {
    int n = blockIdx.x;
    int h = threadIdx.x >> 6;
    int lane = threadIdx.x & 63;
    if (h >= H) return;
    int start = rowptr[n], end = rowptr[n + 1];
    const float* ss = SS + (size_t)h * N;
    float sd = SD[(size_t)h * N + n];
    float* att = ATT + (size_t)h * N_EDGES;
    float m = -1e30f, s = 0.f;
    for (int e = start + lane; e < end; e += 64) {
        float sc = ss[esrc[e]] + sd;
        sc = sc > 0.f ? sc : ALPHA * sc;
        float mn = fmaxf(m, sc);
        s = s * __expf(m - mn) + __expf(sc - mn);
        m = mn;
    }
#pragma unroll
    for (int off = 1; off < 64; off <<= 1) {
        float mo = __shfl_xor(m, off);
        float so = __shfl_xor(s, off);
        float mn = fmaxf(m, mo);
        s = s * __expf(m - mn) + so * __expf(mo - mn);
        m = mn;
    }
    float inv = 1.f / (s + GAT_EPS);
    for (int e = start + lane; e < end; e += 64) {
        float sc = ss[esrc[e]] + sd;
        sc = sc > 0.f ? sc : ALPHA * sc;
        att[e] = __expf(sc - m) * inv;
    }
}

// ---------------- aggregate Fout=256 layers: fp8 gather, one launch, N*8 grid ----------------
__global__ __launch_bounds__(64) void agg256_kernel(const unsigned char* __restrict__ WH8,
                                                    const int* __restrict__ rowptr,
                                                    const int* __restrict__ esrc,
                                                    const float* __restrict__ ATT,
                                                    _Float16* __restrict__ X16,
                                                    int use_skip, int N) {
    int id = blockIdx.x;
    int tile = id & 7, n = id >> 3;
    int h = tile >> 1;
    int lane = threadIdx.x;
    int base = tile * 128 + lane * 2;
    int start = rowptr[n], end = rowptr[n + 1];
    const float* ap = ATT + (size_t)h * N_EDGES;
    const unsigned char* W = WH8 + base;
    float a0 = 0.f, a1 = 0.f;
    int e = start;
    for (; e + 4 <= end; e += 4) {
        int i0 = esrc[e], i1 = esrc[e + 1], i2 = esrc[e + 2], i3 = esrc[e + 3];
        float p0 = ap[e], p1 = ap[e + 1], p2 = ap[e + 2], p3 = ap[e + 3];
        unsigned short w0 = *(const unsigned short*)(W + (size_t)i0 * 1024);
        unsigned short w1 = *(const unsigned short*)(W + (size_t)i1 * 1024);
        unsigned short w2 = *(const unsigned short*)(W + (size_t)i2 * 1024);
        unsigned short w3 = *(const unsigned short*)(W + (size_t)i3 * 1024);
        f32x2 f0 = __builtin_amdgcn_cvt_pk_f32_fp8((int)w0, false);
        f32x2 f1 = __builtin_amdgcn_cvt_pk_f32_fp8((int)w1, false);
        f32x2 f2 = __builtin_amdgcn_cvt_pk_f32_fp8((int)w2, false);
        f32x2 f3 = __builtin_amdgcn_cvt_pk_f32_fp8((int)w3, false);
        a0 += p0 * f0.x + p1 * f1.x + p2 * f2.x + p3 * f3.x;
        a1 += p0 * f0.y + p1 * f1.y + p2 * f2.y + p3 * f3.y;
    }
    for (; e < end; e++) {
        unsigned short w = *(const unsigned short*)(W + (size_t)esrc[e] * 1024);
        f32x2 f = __builtin_amdgcn_cvt_pk_f32_fp8((int)w, false);
        a0 += ap[e] * f.x;
        a1 += ap[e] * f.y;
    }
    size_t o = (size_t)n * 1024 + base;
    float v0, v1;
    if (use_skip) {
        half2t sk = *(const half2t*)(X16 + o);
        v0 = elu1(elu1(a0) + (float)sk.x);
        v1 = elu1(elu1(a1) + (float)sk.y);
    } else {
        v0 = elu1(elu1(a0));
        v1 = elu1(elu1(a1));
    }
    half2t r; r.x = (_Float16)v0; r.y = (_Float16)v1;
    *(half2t*)(X16 + o) = r;
}

// ---------------- layer 3: fused all-heads fp8 gather, mean + sigmoid ----------------
__global__ __launch_bounds__(128) void agg726_kernel(const unsigned char* __restrict__ WH8,
                                                     const int* __restrict__ rowptr,
                                                     const int* __restrict__ esrc,
                                                     const float* __restrict__ ATT,
                                                     float* __restrict__ out, int N) {
    __shared__ float part[2][128];
    int t = threadIdx.x, n = blockIdx.x;
    int lane = t & 63, wv = t >> 6;
    int h0 = wv * 3;
    int start = rowptr[n], end = rowptr[n + 1];
    float acc[3][2] = {};
    for (int e = start; e < end; e++) {
        int s = esrc[e];
        float p0 = ATT[(size_t)(h0 + 0) * N_EDGES + e];
        float p1 = ATT[(size_t)(h0 + 1) * N_EDGES + e];
        float p2 = ATT[(size_t)(h0 + 2) * N_EDGES + e];
        const unsigned char* row = WH8 + (size_t)s * 768 + h0 * 121;
        acc[0][0] += p0 * fp82f(row[lane]);
        acc[1][0] += p1 * fp82f(row[121 + lane]);
        acc[2][0] += p2 * fp82f(row[242 + lane]);
        if (lane < 57) {
            acc[0][1] += p0 * fp82f(row[64 + lane]);
            acc[1][1] += p1 * fp82f(row[185 + lane]);
            acc[2][1] += p2 * fp82f(row[306 + lane]);
        }
    }
    float s0 = acc[0][0] + acc[1][0] + acc[2][0];
    float s1 = acc[0][1] + acc[1][1] + acc[2][1];
    part[wv][lane] = s0;
    if (lane < 57) part[wv][64 + lane] = s1;
    __syncthreads();
    if (t < 121) {
        float tot = (part[0][t] + part[1][t]) * (1.f / 6.f);
        out[(size_t)n * 121 + t] = 1.f / (1.f + __expf(-tot));
    }
}

extern "C" void kernel_launch(void* const* d_in, const int* in_sizes, int n_in,
                              void* d_out, int out_size, void* d_ws, size_t ws_size,
                              hipStream_t stream) {
    const float* x  = (const float*)d_in[0];
    const int*   ei = (const int*)d_in[1];
    const float* W1 = (const float*)d_in[2];
    const float* a1 = (const float*)d_in[3];
    const float* W2 = (const float*)d_in[4];
    const float* a2 = (const float*)d_in[5];
    const float* W3 = (const float*)d_in[6];
    const float* a3 = (const float*)d_in[7];
    float* out = (float*)d_out;
    const int N = N_NODES, E = N_EDGES;
    const int* src = ei;
    const int* dst = ei + E;

    char* ws = (char*)d_ws;
    size_t off = 0;
    auto alloc = [&](size_t b) { size_t o = off; off += (b + 255) & ~(size_t)255; return o; };
    _Float16* X16  = (_Float16*)(ws + alloc((size_t)MPAD * 1024 * 2));  // x1 then x2 (fp16)
    unsigned char* WH8 = (unsigned char*)(ws + alloc((size_t)MPAD * 1024)); // per-layer Wh (fp8)
    _Float16* BT16 = (_Float16*)(ws + alloc((size_t)BT_ROWS * 1024 * 2));
    _Float16* A1   = (_Float16*)(ws + alloc((size_t)MPAD * 64 * 2));
    _Float16* BT1  = (_Float16*)(ws + alloc((size_t)BT_ROWS * 64 * 2));
    float* SPRE   = (float*)(ws + alloc((size_t)12 * N * 4));
    float* ATT    = (float*)(ws + alloc((size_t)6 * E * 4));
    int*   rowptr = (int*)(ws + alloc((size_t)(N + 1) * 4));
    int*   cursor = (int*)(ws + alloc((size_t)N * 4));
    int*   counts = (int*)(ws + alloc((size_t)N * 4));
    int*   excl   = (int*)(ws + alloc((size_t)N * 4));
    int*   partial= (int*)(ws + alloc((size_t)SCAN_BLKS * 4));
    int*   esrc   = (int*)(ws + alloc((size_t)E * 4));

    // CSR by dst
    hipMemsetAsync(counts, 0, (size_t)N * 4, stream);
    hist_kernel<<<(E + 255) / 256, 256, 0, stream>>>(dst, counts, E);
    scan1_kernel<<<SCAN_BLKS, 256, 0, stream>>>(counts, excl, partial, N);
    scan2_kernel<<<1, 128, 0, stream>>>(partial);
    scan3_kernel<<<SCAN_BLKS, 256, 0, stream>>>(excl, partial, rowptr, cursor, N, E);
    scatter_kernel<<<(E + 255) / 256, 256, 0, stream>>>(src, dst, cursor, esrc, E);
    hipMemsetAsync(X16 + (size_t)N * 1024, 0, (size_t)(MPAD - N) * 1024 * 2, stream);

    // ---- layer 1: 50 -> 4x256 concat ----
    pack_x16<<<MPAD * 64 / 256, 256, 0, stream>>>(x, A1);
    pack_bt1<<<1024 * 64 / 256, 256, 0, stream>>>(W1, BT1);
    wtilde_kernel<<<dim3(64, 8), 64, 0, stream>>>(W1, a1, BT1, 50, 64, 256, 4, 1024);
    gemm_f16<<<8 * RHI * 9, 256, 0, stream>>>(A1, BT1, WH8, SPRE, N, 1024, 1024, 64, 9);
    att_kernel<<<N, 256, 0, stream>>>(rowptr, esrc, SPRE, SPRE + 4 * N, ATT, N, 4);
    agg256_kernel<<<N * 8, 64, 0, stream>>>(WH8, rowptr, esrc, ATT, X16, 0, N);

    // ---- layer 2: 1024 -> 4x256 concat + skip ----
    pack_bt16<<<dim3(4, 1024), 256, 0, stream>>>(W2, BT16, 256, 1024);
    wtilde_kernel<<<dim3(1024, 8), 64, 0, stream>>>(W2, a2, BT16, 1024, 1024, 256, 4, 1024);
    gemm_f16<<<8 * RHI * 9, 256, 0, stream>>>(X16, BT16, WH8, SPRE, N, 1024, 1024, 1024, 9);
    att_kernel<<<N, 256, 0, stream>>>(rowptr, esrc, SPRE, SPRE + 4 * N, ATT, N, 4);
    agg256_kernel<<<N * 8, 64, 0, stream>>>(WH8, rowptr, esrc, ATT, X16, 1, N);

    // ---- layer 3: 1024 -> 6x121, mean over heads, sigmoid ----
    pack_bt16<<<dim3(4, 768), 256, 0, stream>>>(W3, BT16, 121, 726);
    wtilde_kernel<<<dim3(1024, 12), 64, 0, stream>>>(W3, a3, BT16, 1024, 1024, 121, 6, 726);
    gemm_f16<<<8 * RHI * 6, 256, 0, stream>>>(X16, BT16, WH8, SPRE, N, 726, 768, 1024, 6);
    att_kernel<<<N, 384, 0, stream>>>(rowptr, esrc, SPRE, SPRE + 6 * N, ATT, N, 6);
    agg726_kernel<<<N, 128, 0, stream>>>(WH8, rowptr, esrc, ATT, out, N);
}

// Round 12
// 480.936 us; speedup vs baseline: 1.9504x; 1.0893x over previous
//
#include <hip/hip_runtime.h>
#include <cstdint>

#define N_NODES 20000
#define N_EDGES 320000
#define ALPHA 0.2f
#define GAT_EPS 1e-16f
#define MPAD 20096           // 157 * 128
#define RBLK 157
#define RHI 20               // ceil(157/8)
#define SCAN_BLKS 80
#define BT_ROWS 1152         // 9 col-blocks * 128

typedef __attribute__((ext_vector_type(8))) _Float16 half8;
typedef __attribute__((ext_vector_type(4))) _Float16 half4t;
typedef __attribute__((ext_vector_type(16))) float f32x16;
typedef __attribute__((ext_vector_type(2))) float f32x2;

__device__ __forceinline__ float elu1(float x) { return x > 0.f ? x : __expf(x) - 1.f; }

__device__ __forceinline__ unsigned char f2fp8(float x) {
    return (unsigned char)(__builtin_amdgcn_cvt_pk_fp8_f32(x, 0.f, 0, false) & 0xff);
}

__device__ __forceinline__ void async16(const void* g, void* l) {
    __builtin_amdgcn_global_load_lds(
        (const __attribute__((address_space(1))) unsigned int*)g,
        (__attribute__((address_space(3))) unsigned int*)l, 16, 0, 0);
}

// ---------------- CSR build ----------------
__global__ void hist_kernel(const int* __restrict__ dst, int* __restrict__ counts, int E) {
    int e = blockIdx.x * blockDim.x + threadIdx.x;
    if (e < E) atomicAdd(&counts[dst[e]], 1);
}

__global__ void scan1_kernel(const int* __restrict__ counts, int* __restrict__ excl,
                             int* __restrict__ partial, int N) {
    __shared__ int sh[256];
    int t = threadIdx.x, b = blockIdx.x;
    int i = b * 256 + t;
    int v = (i < N) ? counts[i] : 0;
    sh[t] = v;
    __syncthreads();
    for (int d = 1; d < 256; d <<= 1) {
        int x = (t >= d) ? sh[t - d] : 0;
        __syncthreads();
        sh[t] += x;
        __syncthreads();
    }
    if (i < N) excl[i] = sh[t] - v;
    if (t == 255) partial[b] = sh[255];
}

__global__ void scan2_kernel(int* __restrict__ partial) {
    __shared__ int sh[128];
    int t = threadIdx.x;
    int v = (t < SCAN_BLKS) ? partial[t] : 0;
    sh[t] = v;
    __syncthreads();
    for (int d = 1; d < 128; d <<= 1) {
        int x = (t >= d) ? sh[t - d] : 0;
        __syncthreads();
        sh[t] += x;
        __syncthreads();
    }
    if (t < SCAN_BLKS) partial[t] = sh[t] - v;
}

__global__ void scan3_kernel(const int* __restrict__ excl, const int* __restrict__ partial,
                             int* __restrict__ rowptr, int* __restrict__ cursor, int N, int E) {
    int t = threadIdx.x, b = blockIdx.x;
    int i = b * 256 + t;
    if (i < N) {
        int v = excl[i] + partial[b];
        rowptr[i] = v;
        cursor[i] = v;
    }
    if (i == 0) rowptr[N] = E;
}

__global__ void scatter_kernel(const int* __restrict__ src, const int* __restrict__ dst,
                               int* __restrict__ cursor, int* __restrict__ esrc, int E) {
    int e = blockIdx.x * blockDim.x + threadIdx.x;
    if (e < E) {
        int p = atomicAdd(&cursor[dst[e]], 1);
        esrc[p] = src[e];
    }
}

// ---------------- packs ----------------
__global__ void pack_x16(const float* __restrict__ x, _Float16* __restrict__ A) {
    int idx = blockIdx.x * 256 + threadIdx.x;   // MPAD*64
    int r = idx >> 6, c = idx & 63;
    float v = (r < N_NODES && c < 50) ? x[r * 50 + c] : 0.f;
    A[idx] = (_Float16)v;
}

__global__ void pack_bt1(const float* __restrict__ W, _Float16* __restrict__ Bt) {
    int idx = blockIdx.x * 256 + threadIdx.x;   // 1024*64
    int c = idx >> 6, k = idx & 63;
    int h = c >> 8, f = c & 255;
    float v = (k < 50) ? W[((size_t)h * 50 + k) * 256 + f] : 0.f;
    Bt[idx] = (_Float16)v;
}

// generic: BT row c -> head h=c/Fpad, col f=c%Fpad; zero for f>=F (alignment pad)
__global__ void pack_bt16(const float* __restrict__ W, _Float16* __restrict__ Bt,
                          int F, int Fpad, int Ctot) {
    int c = blockIdx.y;
    int k = blockIdx.x * blockDim.x + threadIdx.x;
    float v = 0.f;
    if (c < Ctot) {
        int h = c / Fpad, f = c - h * Fpad;
        if (f < F) v = W[(size_t)h * 1024 * F + (size_t)k * F + f];
    }
    Bt[(size_t)c * 1024 + k] = (_Float16)v;
}

// W~ cols appended at BT rows [Nfeat, Nfeat+2H); gridDim.y MUST be 2*H.
__global__ __launch_bounds__(64) void wtilde_kernel(const float* __restrict__ W,
                                                    const float* __restrict__ a,
                                                    _Float16* __restrict__ BT, int Kreal,
                                                    int Kdim, int F, int H, int Nfeat) {
    int k = blockIdx.x, j = blockIdx.y;
    if (j >= 2 * H) return;
    int lane = threadIdx.x;
    int h = j < H ? j : j - H;
    int ao = j < H ? 0 : F;
    float s = 0.f;
    if (k < Kreal) {
        const float* wp = W + ((size_t)h * Kreal + k) * F;
        const float* ap = a + (size_t)h * 2 * F + ao;
        for (int f = lane; f < F; f += 64) s += wp[f] * ap[f];
    }
#pragma unroll
    for (int off = 32; off; off >>= 1) s += __shfl_down(s, off);
    if (lane == 0) BT[(size_t)(Nfeat + j) * Kdim + k] = (_Float16)s;
}

// ---------------- fp16 MFMA GEMM (32x32x16) -> fp8 Wh + fp32 score cols; XCD-swizzled ------
__global__ __launch_bounds__(256) void gemm_f16(const _Float16* __restrict__ A,
                                                const _Float16* __restrict__ BT,
                                                unsigned char* __restrict__ C8,
                                                float* __restrict__ SPRE,
                                                int M, int Nfeat, int ld, int Kdim, int Cblk) {
    int id = blockIdx.x;
    int xm = id & 7, q = id >> 3;
    int cb = q % Cblk, rh = q / Cblk;
    int rb = rh * 8 + xm;
    if (rb >= RBLK) return;
    __shared__ __align__(16) _Float16 sA[128 * 64];
    __shared__ __align__(16) _Float16 sB[128 * 64];
    int t = threadIdx.x;
    int row0 = rb * 128, col0 = cb * 128;
    int lane = t & 63, wave = t >> 6;
    int wm = wave >> 1, wn = wave & 1;
    int l31 = lane & 31;
    int lhi = lane >> 5;

    const _Float16* gA = A + (size_t)row0 * Kdim;
    const _Float16* gB = BT + (size_t)col0 * Kdim;

    int sR[4], sgl[4];
#pragma unroll
    for (int i = 0; i < 4; i++) {
        int m = i * 256 + t;
        sR[i] = m >> 3;
        sgl[i] = (m & 7) ^ (sR[i] & 7);
    }

    f32x16 acc[2][2] = {};

    for (int k0 = 0; k0 < Kdim; k0 += 64) {
        __syncthreads();
#pragma unroll
        for (int i = 0; i < 4; i++) {
            const _Float16* pa = gA + (size_t)sR[i] * Kdim + k0 + sgl[i] * 8;
            const _Float16* pb = gB + (size_t)sR[i] * Kdim + k0 + sgl[i] * 8;
            async16(pa, sA + (i * 256 + t) * 8);
            async16(pb, sB + (i * 256 + t) * 8);
        }
        __syncthreads();
#pragma unroll
        for (int kk = 0; kk < 4; kk++) {
            int g = kk * 2 + lhi;
            half8 af[2], bf[2];
#pragma unroll
            for (int mt = 0; mt < 2; mt++) {
                int R = wm * 64 + mt * 32 + l31;
                int gp = g ^ (R & 7);
                af[mt] = *(const half8*)(sA + R * 64 + gp * 8);
            }
#pragma unroll
            for (int nt = 0; nt < 2; nt++) {
                int R = wn * 64 + nt * 32 + l31;
                int gp = g ^ (R & 7);
                bf[nt] = *(const half8*)(sB + R * 64 + gp * 8);
            }
#pragma unroll
            for (int mt = 0; mt < 2; mt++)
#pragma unroll
                for (int nt = 0; nt < 2; nt++)
                    acc[mt][nt] = __builtin_amdgcn_mfma_f32_32x32x16_f16(af[mt], bf[nt], acc[mt][nt], 0, 0, 0);
        }
    }

    int cb32 = col0 + wn * 64 + l31;
    int rb32 = row0 + wm * 64 + 4 * lhi;
#pragma unroll
    for (int mt = 0; mt < 2; mt++)
#pragma unroll
        for (int nt = 0; nt < 2; nt++) {
            int gc = cb32 + nt * 32;
            if (gc < Nfeat) {
#pragma unroll
                for (int r = 0; r < 16; r++) {
                    int gr = rb32 + mt * 32 + (r & 3) + 8 * (r >> 2);
                    if (gr < M) C8[(size_t)gr * ld + gc] = f2fp8(acc[mt][nt][r]);
                }
            } else if (gc < Nfeat + 12) {
                int j = gc - Nfeat;
#pragma unroll
                for (int r = 0; r < 16; r++) {
                    int gr = rb32 + mt * 32 + (r & 3) + 8 * (r >> 2);
                    if (gr < M) SPRE[(size_t)j * N_NODES + gr] = acc[mt][nt][r];
                }
            }
        }
}

// ---------------- per-edge attention: online softmax, head-per-wave ----------------
__global__ void att_kernel(const int* __restrict__ rowptr,
                           const int* __restrict__ esrc,
                           const float* __restrict__ SS,
                           const float* __restrict__ SD,
                           float* __restrict__ ATT, int N, int H) {
    int n = blockIdx.x;
    int h = threadIdx.x >> 6;
    int lane = threadIdx.x & 63;
    if (h >= H) return;
    int start = rowptr[n], end = rowptr[n + 1];
    const float* ss = SS + (size_t)h * N;
    float sd = SD[(size_t)h * N + n];
    float* att = ATT + (size_t)h * N_EDGES;
    float m = -1e30f, s = 0.f;
    for (int e = start + lane; e < end; e += 64) {
        float sc = ss[esrc[e]] + sd;
        sc = sc > 0.f ? sc : ALPHA * sc;
        float mn = fmaxf(m, sc);
        s = s * __expf(m - mn) + __expf(sc - mn);
        m = mn;
    }
#pragma unroll
    for (int off = 1; off < 64; off <<= 1) {
        float mo = __shfl_xor(m, off);
        float so = __shfl_xor(s, off);
        float mn = fmaxf(m, mo);
        s = s * __expf(m - mn) + so * __expf(mo - mn);
        m = mn;
    }
    float inv = 1.f / (s + GAT_EPS);
    for (int e = start + lane; e < end; e += 64) {
        float sc = ss[esrc[e]] + sd;
        sc = sc > 0.f ? sc : ALPHA * sc;
        att[e] = __expf(sc - m) * inv;
    }
}

// ---------------- aggregate Fout=256 layers: dword fp8 gather, N*4 grid ----------------
// one block per (node, head); lane covers 4 fp8 cols -> 256 B per wave-gather; unroll 8.
__global__ __launch_bounds__(64) void agg256_kernel(const unsigned char* __restrict__ WH8,
                                                    const int* __restrict__ rowptr,
                                                    const int* __restrict__ esrc,
                                                    const float* __restrict__ ATT,
                                                    _Float16* __restrict__ X16,
                                                    int use_skip, int N) {
    int id = blockIdx.x;
    int h = id & 3, n = id >> 2;
    int lane = threadIdx.x;
    int base = h * 256 + lane * 4;
    int start = rowptr[n], end = rowptr[n + 1];
    const float* ap = ATT + (size_t)h * N_EDGES;
    const unsigned char* W = WH8 + base;
    float a0 = 0.f, a1 = 0.f, a2 = 0.f, a3 = 0.f;
    int e = start;
    for (; e + 8 <= end; e += 8) {
#pragma unroll
        for (int u = 0; u < 8; u += 4) {
            int i0 = esrc[e + u], i1 = esrc[e + u + 1], i2 = esrc[e + u + 2], i3 = esrc[e + u + 3];
            float p0 = ap[e + u], p1 = ap[e + u + 1], p2 = ap[e + u + 2], p3 = ap[e + u + 3];
            unsigned int w0 = *(const unsigned int*)(W + (size_t)i0 * 1024);
            unsigned int w1 = *(const unsigned int*)(W + (size_t)i1 * 1024);
            unsigned int w2 = *(const unsigned int*)(W + (size_t)i2 * 1024);
            unsigned int w3 = *(const unsigned int*)(W + (size_t)i3 * 1024);
            f32x2 l0 = __builtin_amdgcn_cvt_pk_f32_fp8((int)w0, false);
            f32x2 h0v = __builtin_amdgcn_cvt_pk_f32_fp8((int)w0, true);
            f32x2 l1 = __builtin_amdgcn_cvt_pk_f32_fp8((int)w1, false);
            f32x2 h1v = __builtin_amdgcn_cvt_pk_f32_fp8((int)w1, true);
            f32x2 l2 = __builtin_amdgcn_cvt_pk_f32_fp8((int)w2, false);
            f32x2 h2v = __builtin_amdgcn_cvt_pk_f32_fp8((int)w2, true);
            f32x2 l3 = __builtin_amdgcn_cvt_pk_f32_fp8((int)w3, false);
            f32x2 h3v = __builtin_amdgcn_cvt_pk_f32_fp8((int)w3, true);
            a0 += p0 * l0.x + p1 * l1.x + p2 * l2.x + p3 * l3.x;
            a1 += p0 * l0.y + p1 * l1.y + p2 * l2.y + p3 * l3.y;
            a2 += p0 * h0v.x + p1 * h1v.x + p2 * h2v.x + p3 * h3v.x;
            a3 += p0 * h0v.y + p1 * h1v.y + p2 * h2v.y + p3 * h3v.y;
        }
    }
    for (; e < end; e++) {
        float p = ap[e];
        unsigned int w = *(const unsigned int*)(W + (size_t)esrc[e] * 1024);
        f32x2 lo = __builtin_amdgcn_cvt_pk_f32_fp8((int)w, false);
        f32x2 hi = __builtin_amdgcn_cvt_pk_f32_fp8((int)w, true);
        a0 += p * lo.x; a1 += p * lo.y; a2 += p * hi.x; a3 += p * hi.y;
    }
    size_t o = (size_t)n * 1024 + base;
    float v0, v1, v2, v3;
    if (use_skip) {
        half4t sk = *(const half4t*)(X16 + o);
        v0 = elu1(elu1(a0) + (float)sk.x);
        v1 = elu1(elu1(a1) + (float)sk.y);
        v2 = elu1(elu1(a2) + (float)sk.z);
        v3 = elu1(elu1(a3) + (float)sk.w);
    } else {
        v0 = elu1(elu1(a0)); v1 = elu1(elu1(a1));
        v2 = elu1(elu1(a2)); v3 = elu1(elu1(a3));
    }
    half4t r;
    r.x = (_Float16)v0; r.y = (_Float16)v1; r.z = (_Float16)v2; r.w = (_Float16)v3;
    *(half4t*)(X16 + o) = r;
}

// ---------------- layer 3: head stride 124 (zero-padded), uchar2 gathers ----------------
// Wh3 row = 6*124 = 744 B (ld 768). Wave wv handles heads wv*3..wv*3+2; lanes 0..61 load
// uchar2 at h*124 + 2*lane. Pad cols 121..123 are exact zeros from the GEMM -> no masking.
__global__ __launch_bounds__(128) void agg726_kernel(const unsigned char* __restrict__ WH8,
                                                     const int* __restrict__ rowptr,
                                                     const int* __restrict__ esrc,
                                                     const float* __restrict__ ATT,
                                                     float* __restrict__ out, int N) {
    __shared__ float part[2][124];
    int t = threadIdx.x, n = blockIdx.x;
    int lane = t & 63, wv = t >> 6;
    int h0 = wv * 3;
    int start = rowptr[n], end = rowptr[n + 1];
    float acc[3][2] = {};
    if (lane < 62) {
        const unsigned char* W0 = WH8 + (h0 + 0) * 124 + 2 * lane;
        const unsigned char* W1 = WH8 + (h0 + 1) * 124 + 2 * lane;
        const unsigned char* W2 = WH8 + (h0 + 2) * 124 + 2 * lane;
        const float* ap0 = ATT + (size_t)(h0 + 0) * N_EDGES;
        const float* ap1 = ATT + (size_t)(h0 + 1) * N_EDGES;
        const float* ap2 = ATT + (size_t)(h0 + 2) * N_EDGES;
        int e = start;
        for (; e + 2 <= end; e += 2) {
            size_t sa = (size_t)esrc[e] * 768, sb = (size_t)esrc[e + 1] * 768;
            float pa0 = ap0[e], pa1 = ap1[e], pa2 = ap2[e];
            float pb0 = ap0[e + 1], pb1 = ap1[e + 1], pb2 = ap2[e + 1];
            unsigned short wa0 = *(const unsigned short*)(W0 + sa);
            unsigned short wa1 = *(const unsigned short*)(W1 + sa);
            unsigned short wa2 = *(const unsigned short*)(W2 + sa);
            unsigned short wb0 = *(const unsigned short*)(W0 + sb);
            unsigned short wb1 = *(const unsigned short*)(W1 + sb);
            unsigned short wb2 = *(const unsigned short*)(W2 + sb);
            f32x2 fa0 = __builtin_amdgcn_cvt_pk_f32_fp8((int)wa0, false);
            f32x2 fa1 = __builtin_amdgcn_cvt_pk_f32_fp8((int)wa1, false);
            f32x2 fa2 = __builtin_amdgcn_cvt_pk_f32_fp8((int)wa2, false);
            f32x2 fb0 = __builtin_amdgcn_cvt_pk_f32_fp8((int)wb0, false);
            f32x2 fb1 = __builtin_amdgcn_cvt_pk_f32_fp8((int)wb1, false);
            f32x2 fb2 = __builtin_amdgcn_cvt_pk_f32_fp8((int)wb2, false);
            acc[0][0] += pa0 * fa0.x + pb0 * fb0.x;
            acc[0][1] += pa0 * fa0.y + pb0 * fb0.y;
            acc[1][0] += pa1 * fa1.x + pb1 * fb1.x;
            acc[1][1] += pa1 * fa1.y + pb1 * fb1.y;
            acc[2][0] += pa2 * fa2.x + pb2 * fb2.x;
            acc[2][1] += pa2 * fa2.y + pb2 * fb2.y;
        }
        for (; e < end; e++) {
            size_t sa = (size_t)esrc[e] * 768;
            float p0 = ap0[e], p1 = ap1[e], p2 = ap2[e];
            f32x2 f0 = __builtin_amdgcn_cvt_pk_f32_fp8((int)*(const unsigned short*)(W0 + sa), false);
            f32x2 f1 = __builtin_amdgcn_cvt_pk_f32_fp8((int)*(const unsigned short*)(W1 + sa), false);
            f32x2 f2 = __builtin_amdgcn_cvt_pk_f32_fp8((int)*(const unsigned short*)(W2 + sa), false);
            acc[0][0] += p0 * f0.x; acc[0][1] += p0 * f0.y;
            acc[1][0] += p1 * f1.x; acc[1][1] += p1 * f1.y;
            acc[2][0] += p2 * f2.x; acc[2][1] += p2 * f2.y;
        }
        part[wv][2 * lane]     = acc[0][0] + acc[1][0] + acc[2][0];
        part[wv][2 * lane + 1] = acc[0][1] + acc[1][1] + acc[2][1];
    }
    __syncthreads();
    if (t < 121) {
        float tot = (part[0][t] + part[1][t]) * (1.f / 6.f);
        out[(size_t)n * 121 + t] = 1.f / (1.f + __expf(-tot));
    }
}

extern "C" void kernel_launch(void* const* d_in, const int* in_sizes, int n_in,
                              void* d_out, int out_size, void* d_ws, size_t ws_size,
                              hipStream_t stream) {
    const float* x  = (const float*)d_in[0];
    const int*   ei = (const int*)d_in[1];
    const float* W1 = (const float*)d_in[2];
    const float* a1 = (const float*)d_in[3];
    const float* W2 = (const float*)d_in[4];
    const float* a2 = (const float*)d_in[5];
    const float* W3 = (const float*)d_in[6];
    const float* a3 = (const float*)d_in[7];
    float* out = (float*)d_out;
    const int N = N_NODES, E = N_EDGES;
    const int* src = ei;
    const int* dst = ei + E;

    char* ws = (char*)d_ws;
    size_t off = 0;
    auto alloc = [&](size_t b) { size_t o = off; off += (b + 255) & ~(size_t)255; return o; };
    _Float16* X16  = (_Float16*)(ws + alloc((size_t)MPAD * 1024 * 2));  // x1 then x2 (fp16)
    unsigned char* WH8 = (unsigned char*)(ws + alloc((size_t)MPAD * 1024)); // per-layer Wh (fp8)
    _Float16* BT16 = (_Float16*)(ws + alloc((size_t)BT_ROWS * 1024 * 2));
    _Float16* A1   = (_Float16*)(ws + alloc((size_t)MPAD * 64 * 2));
    _Float16* BT1  = (_Float16*)(ws + alloc((size_t)BT_ROWS * 64 * 2));
    float* SPRE   = (float*)(ws + alloc((size_t)12 * N * 4));
    float* ATT    = (float*)(ws + alloc((size_t)6 * E * 4));
    int*   rowptr = (int*)(ws + alloc((size_t)(N + 1) * 4));
    int*   cursor = (int*)(ws + alloc((size_t)N * 4));
    int*   counts = (int*)(ws + alloc((size_t)N * 4));
    int*   excl   = (int*)(ws + alloc((size_t)N * 4));
    int*   partial= (int*)(ws + alloc((size_t)SCAN_BLKS * 4));
    int*   esrc   = (int*)(ws + alloc((size_t)E * 4));

    // CSR by dst
    hipMemsetAsync(counts, 0, (size_t)N * 4, stream);
    hist_kernel<<<(E + 255) / 256, 256, 0, stream>>>(dst, counts, E);
    scan1_kernel<<<SCAN_BLKS, 256, 0, stream>>>(counts, excl, partial, N);
    scan2_kernel<<<1, 128, 0, stream>>>(partial);
    scan3_kernel<<<SCAN_BLKS, 256, 0, stream>>>(excl, partial, rowptr, cursor, N, E);
    scatter_kernel<<<(E + 255) / 256, 256, 0, stream>>>(src, dst, cursor, esrc, E);
    hipMemsetAsync(X16 + (size_t)N * 1024, 0, (size_t)(MPAD - N) * 1024 * 2, stream);

    // ---- layer 1: 50 -> 4x256 concat ----
    pack_x16<<<MPAD * 64 / 256, 256, 0, stream>>>(x, A1);
    pack_bt1<<<1024 * 64 / 256, 256, 0, stream>>>(W1, BT1);
    wtilde_kernel<<<dim3(64, 8), 64, 0, stream>>>(W1, a1, BT1, 50, 64, 256, 4, 1024);
    gemm_f16<<<8 * RHI * 9, 256, 0, stream>>>(A1, BT1, WH8, SPRE, N, 1024, 1024, 64, 9);
    att_kernel<<<N, 256, 0, stream>>>(rowptr, esrc, SPRE, SPRE + 4 * N, ATT, N, 4);
    agg256_kernel<<<N * 4, 64, 0, stream>>>(WH8, rowptr, esrc, ATT, X16, 0, N);

    // ---- layer 2: 1024 -> 4x256 concat + skip ----
    pack_bt16<<<dim3(4, 1024), 256, 0, stream>>>(W2, BT16, 256, 256, 1024);
    wtilde_kernel<<<dim3(1024, 8), 64, 0, stream>>>(W2, a2, BT16, 1024, 1024, 256, 4, 1024);
    gemm_f16<<<8 * RHI * 9, 256, 0, stream>>>(X16, BT16, WH8, SPRE, N, 1024, 1024, 1024, 9);
    att_kernel<<<N, 256, 0, stream>>>(rowptr, esrc, SPRE, SPRE + 4 * N, ATT, N, 4);
    agg256_kernel<<<N * 4, 64, 0, stream>>>(WH8, rowptr, esrc, ATT, X16, 1, N);

    // ---- layer 3: 1024 -> 6x121 (stride 124, zero-padded), mean + sigmoid ----
    pack_bt16<<<dim3(4, 744), 256, 0, stream>>>(W3, BT16, 121, 124, 744);
    wtilde_kernel<<<dim3(1024, 12), 64, 0, stream>>>(W3, a3, BT16, 1024, 1024, 121, 6, 744);
    gemm_f16<<<8 * RHI * 6, 256, 0, stream>>>(X16, BT16, WH8, SPRE, N, 744, 768, 1024, 6);
    att_kernel<<<N, 384, 0, stream>>>(rowptr, esrc, SPRE, SPRE + 6 * N, ATT, N, 6);
    agg726_kernel<<<N, 128, 0, stream>>>(WH8, rowptr, esrc, ATT, out, N);
}